// Round 8
// baseline (896.668 us; speedup 1.0000x reference)
//
#include <hip/hip_runtime.h>
#include <math.h>

typedef unsigned int u32;
typedef unsigned short u16;
typedef unsigned long long u64;
typedef _Float16 h8v __attribute__((ext_vector_type(8)));
typedef float f4v __attribute__((ext_vector_type(4)));
typedef u32 u4v __attribute__((ext_vector_type(4)));

#define B_ 4
#define C_ 64
#define HW 4096
#define L_ 4096
#define D_ 576
#define MW 256
#define SCALE 10.0f
#define EPS 1e-4f
#define TAU 0.015f
#define PAIRCAP 262144

__device__ __forceinline__ u16 f16b(float x) {
  union { _Float16 h; u16 u; } c; c.h = (_Float16)x; return c.u;
}
__device__ __forceinline__ float f16f(u16 v) {
  union { u16 u; _Float16 h; } c; c.u = v; return (float)c.h;
}

__device__ __forceinline__ void gld16(const void* g, void* l) {
  __builtin_amdgcn_global_load_lds((const __attribute__((address_space(1))) void*)g,
                                   (__attribute__((address_space(3))) void*)l, 16, 0, 0);
}

// ---------- upfront kernels ----------
__global__ __launch_bounds__(256) void k_mp(const float* __restrict__ mask, float* __restrict__ mp) {
  int idx = blockIdx.x * 256 + threadIdx.x;
  int b = idx >> 12, p = idx & 4095;
  int y = p >> 6, x = p & 63;
  const float* mb = mask + (size_t)b * MW * MW;
  float s = 0.f;
  #pragma unroll
  for (int i = 0; i < 4; ++i)
    #pragma unroll
    for (int j = 0; j < 4; ++j)
      s += mb[(y * 4 + i) * MW + x * 4 + j];
  mp[idx] = s * (1.f / 16.f);
}

// m0 (144 blocks) + fm (4096 blocks)
__global__ __launch_bounds__(256) void k_pre2(const float* __restrict__ f, const float* __restrict__ mp,
                                              float* __restrict__ m0, float* __restrict__ fm) {
  int blk = blockIdx.x;
  if (blk < 144) {
    int idx = blk * 256 + threadIdx.x;   // l*9 + t
    int l = idx / 9, t = idx - l * 9;
    int ly = l >> 6, lx = l & 63;
    int i = t / 3, j = t - i * 3;
    int yy = ly + i - 1, xx = lx + j - 1;
    float v = 0.f;
    if ((unsigned)yy < 64u && (unsigned)xx < 64u) v = mp[(yy << 6) + xx];
    m0[idx] = v;
  } else {
    int idx = (blk - 144) * 256 + threadIdx.x;
    int p = idx & 4095;
    int b = idx >> 18;
    fm[idx] = f[idx] * (1.f - mp[(b << 12) + p]);
  }
}

__device__ __forceinline__ float patch_val(const float* __restrict__ img, const float* __restrict__ m0,
                                           int l, int d) {
  int c = d / 9, t = d - c * 9;
  int ly = l >> 6, lx = l & 63;
  int i = t / 3, j = t - i * 3;
  int yy = ly + i - 1, xx = lx + j - 1;
  float v = 0.f;
  if ((unsigned)yy < 64u && (unsigned)xx < 64u) {
    v = img[(c << 12) + (yy << 6) + xx];
    if (m0) v *= m0[l * 9 + t];
  }
  return v;
}

// ---------- per-batch prep (2 elems/thread): w | norme | wT | fp | zero ----------
__global__ __launch_bounds__(256) void k_prep(const float* __restrict__ bimg, const float* __restrict__ fmb,
                                              const float* __restrict__ m0,
                                              u16* __restrict__ w_h, u16* __restrict__ fp_h,
                                              u16* __restrict__ wT_h,
                                              double* __restrict__ norme, float* __restrict__ normv,
                                              int* __restrict__ rcount, int* __restrict__ pcount,
                                              u64* __restrict__ rbest) {
  int blk = blockIdx.x;
  if (blk < 4608) {                      // w patches [l][576] fp16, paired
    int gid = blk * 256 + threadIdx.x;
    int idx = gid * 2;
    int l = idx / D_, d = idx - l * D_;
    u32 h0 = f16b(patch_val(bimg, m0, l, d));
    u32 h1 = f16b(patch_val(bimg, m0, l, d + 1));
    ((u32*)w_h)[gid] = h0 | (h1 << 16);
  } else if (blk < 5632) {               // exact f64 norm + f32 copy
    int l = (blk - 4608) * 4 + (threadIdx.x >> 6);
    int lane = threadIdx.x & 63;
    int ly = l >> 6, lx = l & 63;
    double s = 0.0;
    for (int i = lane; i < D_; i += 64) {
      int c = i / 9, t = i - c * 9;
      int ii = t / 3, jj = t - ii * 3;
      int yy = ly + ii - 1, xx = lx + jj - 1;
      if ((unsigned)yy < 64u && (unsigned)xx < 64u) {
        float wv = bimg[(c << 12) + (yy << 6) + xx] * m0[l * 9 + t];
        s += (double)wv * (double)wv;
      }
    }
    #pragma unroll
    for (int off = 32; off; off >>= 1) s += __shfl_down(s, off);
    if (lane == 0) {
      double n = sqrt(s + (double)EPS);
      norme[l] = n; normv[l] = (float)n;
    }
  } else if (blk < 10752) {              // wT [d<640][4096] fp16, paired along l
    int gid = (blk - 5632) * 256 + threadIdx.x;
    int idx = gid * 2;
    int d = idx >> 12, l = idx & 4095;
    float v0 = 0.f, v1 = 0.f;
    if (d < D_) {
      v0 = patch_val(bimg, m0, l, d);
      v1 = patch_val(bimg, m0, l + 1, d);
    }
    ((u32*)wT_h)[gid] = (u32)f16b(v0) | ((u32)f16b(v1) << 16);
  } else if (blk < 15360) {              // fp patches [q][576] fp16, paired
    int gid = (blk - 10752) * 256 + threadIdx.x;
    int idx = gid * 2;
    int l = idx / D_, d = idx - l * D_;
    u32 h0 = f16b(patch_val(fmb, nullptr, l, d));
    u32 h1 = f16b(patch_val(fmb, nullptr, l, d + 1));
    ((u32*)fp_h)[gid] = h0 | (h1 << 16);
  } else {                               // 16 blocks: zero rbest + counters
    int e = (blk - 15360) * 256 + threadIdx.x;
    rbest[e] = 0ull;
    if (e == 0) { *rcount = 0; *pcount = 0; }
  }
}

// ---------- GEMM1 + fused partial softmax ----------
// block 256x128, 4 waves (wave tile 128x64). A=fp [q][576], B=w [l][576].
// Emits P[q][l]=exp(10(s-bm1)) fp16 and per-(q,j) stats bm1/bi1/bm2/bsum.
#define STAGE1(buf, k0) do {                                                             \
    int bb = (buf) * 24576;                                                              \
    _Pragma("unroll") for (int i_ = 0; i_ < 4; ++i_) {                                   \
      int s_ = tid + i_ * 256; int r_ = s_ >> 2, ks_ = s_ & 3;                           \
      int kg_ = ks_ ^ ((r_ >> 1) & 3);                                                   \
      gld16(A + (u32)(m0 + r_) * 576u + (u32)((k0) + kg_ * 8),                           \
            (char*)lds + bb + s_ * 16); }                                                \
    _Pragma("unroll") for (int i_ = 0; i_ < 2; ++i_) {                                   \
      int s_ = tid + i_ * 256; int r_ = s_ >> 2, ks_ = s_ & 3;                           \
      int kg_ = ks_ ^ ((r_ >> 1) & 3);                                                   \
      gld16(Bm + (u32)(n0 + r_) * 576u + (u32)((k0) + kg_ * 8),                          \
            (char*)lds + bb + 16384 + s_ * 16); }                                        \
  } while (0)

__global__ __launch_bounds__(256, 2) void k_mfma1(
    const u16* __restrict__ A, const u16* __restrict__ Bm, const float* __restrict__ normv,
    u16* __restrict__ P, float* __restrict__ bm1, int* __restrict__ bi1,
    float* __restrict__ bm2, float* __restrict__ bsum)
{
  __shared__ u32 lds[12288];             // 48KB = 2 x (A 16KB + B 8KB)
  u16* ldsu = (u16*)lds;
  const int tid = threadIdx.x;
  const int lane = tid & 63, wid = tid >> 6;
  const int wrM = wid >> 1, wc = wid & 1;
  const int kq = lane >> 4, li = lane & 15;

  int nwg = gridDim.x * gridDim.y;       // 512
  int bid = blockIdx.y * gridDim.x + blockIdx.x;
  int cpx = nwg >> 3;
  int swz = (bid & 7) * cpx + (bid >> 3);
  int bx = swz % gridDim.x, by = swz / gridDim.x;
  const int m0 = by * 256, n0 = bx * 128;

  f4v acc[8][4] = {};

  STAGE1(0, 0);
  __syncthreads();

  for (int kc = 0; kc < 18; ++kc) {
    int cur = kc & 1;
    if (kc + 1 < 18) STAGE1(cur ^ 1, (kc + 1) * 32);
    int cb = cur * 12288;
    h8v ah[8];
    #pragma unroll
    for (int mf = 0; mf < 8; ++mf) {
      int r = wrM * 128 + mf * 16 + li;
      int off = r * 32 + (kq ^ ((r >> 1) & 3)) * 8;
      ah[mf] = *(const h8v*)&ldsu[cb + off];
    }
    #pragma unroll
    for (int nf = 0; nf < 4; ++nf) {
      int r = wc * 64 + nf * 16 + li;
      int off = r * 32 + (kq ^ ((r >> 1) & 3)) * 8;
      h8v bh = *(const h8v*)&ldsu[cb + 8192 + off];
      #pragma unroll
      for (int mf = 0; mf < 8; ++mf)
        acc[mf][nf] = __builtin_amdgcn_mfma_f32_16x16x32_f16(ah[mf], bh, acc[mf][nf], 0, 0, 0);
    }
    if (kc + 1 < 18) {
      asm volatile("s_waitcnt vmcnt(0)" ::: "memory");
      __builtin_amdgcn_s_barrier();
      __builtin_amdgcn_sched_barrier(0);
    }
  }
  __syncthreads();                       // loop fully done; reuse LDS for stats

  float* ldsf = (float*)lds;
  int*   ldsi = (int*)lds;
  // f32-unit regions: bmax [2][256] @0, sum @512, v1 @1024, v2 @1536, i1 @2048

  float invn4[4];
  #pragma unroll
  for (int nf = 0; nf < 4; ++nf) invn4[nf] = 1.0f / normv[n0 + wc * 64 + nf * 16 + li];
  #pragma unroll
  for (int mf = 0; mf < 8; ++mf)
    #pragma unroll
    for (int nf = 0; nf < 4; ++nf)
      #pragma unroll
      for (int rr = 0; rr < 4; ++rr)
        acc[mf][nf][rr] *= invn4[nf];

  // phase 1: per-row max over this wave's 64 cols
  #pragma unroll
  for (int mf = 0; mf < 8; ++mf)
    #pragma unroll
    for (int rr = 0; rr < 4; ++rr) {
      float m4 = fmaxf(fmaxf(acc[mf][0][rr], acc[mf][1][rr]), fmaxf(acc[mf][2][rr], acc[mf][3][rr]));
      #pragma unroll
      for (int d = 1; d < 16; d <<= 1) m4 = fmaxf(m4, __shfl_xor(m4, d));
      if (li == 0) ldsf[wc * 256 + wrM * 128 + mf * 16 + kq * 4 + rr] = m4;
    }
  __syncthreads();

  // phase 2: combined block max; exp + P store + sum + top2
  #pragma unroll
  for (int mf = 0; mf < 8; ++mf)
    #pragma unroll
    for (int rr = 0; rr < 4; ++rr) {
      int r128 = mf * 16 + kq * 4 + rr;
      float bm = fmaxf(ldsf[wrM * 128 + r128], ldsf[256 + wrM * 128 + r128]);
      int m = m0 + wrM * 128 + r128;
      float sum4 = 0.f, v1 = -3.4e38f, v2 = -3.4e38f; int i1 = 0x7fffffff;
      #pragma unroll
      for (int nf = 0; nf < 4; ++nf) {
        float sv = acc[mf][nf][rr];
        int n = n0 + wc * 64 + nf * 16 + li;
        float p = __expf((sv - bm) * SCALE);
        P[(u32)m * 4096u + (u32)n] = f16b(p);
        sum4 += p;
        if (sv > v1 || (sv == v1 && n < i1)) { v2 = v1; v1 = sv; i1 = n; }
        else v2 = fmaxf(v2, sv);
      }
      #pragma unroll
      for (int d = 1; d < 16; d <<= 1) {
        sum4 += __shfl_xor(sum4, d);
        float ov1 = __shfl_xor(v1, d); int oi1 = __shfl_xor(i1, d); float ov2 = __shfl_xor(v2, d);
        if (ov1 > v1 || (ov1 == v1 && oi1 < i1)) { v2 = fmaxf(v1, ov2); v1 = ov1; i1 = oi1; }
        else v2 = fmaxf(v2, ov1);
      }
      if (li == 0) {
        int slot = wc * 256 + wrM * 128 + r128;
        ldsf[512 + slot] = sum4;
        ldsf[1024 + slot] = v1;
        ldsf[1536 + slot] = v2;
        ldsi[2048 + slot] = i1;
      }
    }
  __syncthreads();

  // phase 3: one thread per row: merge wc halves, store stats
  {
    float sA = ldsf[512 + tid], sB = ldsf[512 + 256 + tid];
    float v1a = ldsf[1024 + tid], v1b = ldsf[1024 + 256 + tid];
    float v2a = ldsf[1536 + tid], v2b = ldsf[1536 + 256 + tid];
    int   i1a = ldsi[2048 + tid], i1b = ldsi[2048 + 256 + tid];
    float V1, V2; int I1;
    if (v1b > v1a) { V1 = v1b; I1 = i1b; V2 = fmaxf(v1a, v2b); }
    else           { V1 = v1a; I1 = i1a; V2 = fmaxf(v2a, v1b); }
    int q = m0 + tid, j = n0 >> 7;
    bm1[q * 32 + j] = V1; bi1[q * 32 + j] = I1; bm2[q * 32 + j] = V2;
    bsum[q * 32 + j] = sA + sB;
  }
}

// ---------- softmax reduce across 32 blocks: gmax/argmax/Z/fac/flag ----------
__global__ __launch_bounds__(256) void k_smred(const float* __restrict__ bm1, const int* __restrict__ bi1,
                                               const float* __restrict__ bm2, const float* __restrict__ bsum,
                                               float* __restrict__ fac, float* __restrict__ gm,
                                               float* __restrict__ offs,
                                               int* __restrict__ rlist, int* __restrict__ rcount) {
  int q = blockIdx.x * 4 + (threadIdx.x >> 6);
  int lane = threadIdx.x & 63;
  if (lane >= 32) return;
  float mj = bm1[q * 32 + lane];
  float v1 = mj; int i1 = bi1[q * 32 + lane];
  float v2 = bm2[q * 32 + lane];
  #pragma unroll
  for (int d = 1; d < 32; d <<= 1) {
    float ov1 = __shfl_xor(v1, d); int oi1 = __shfl_xor(i1, d); float ov2 = __shfl_xor(v2, d);
    if (ov1 > v1 || (ov1 == v1 && oi1 < i1)) { v2 = fmaxf(v1, ov2); v1 = ov1; i1 = oi1; }
    else v2 = fmaxf(v2, ov1);
  }
  // v1 = gmax, i1 = argmax, v2 = global second
  float e = __expf((mj - v1) * SCALE);
  float zt = bsum[q * 32 + lane] * e;
  float Z = zt;
  #pragma unroll
  for (int d = 1; d < 32; d <<= 1) Z += __shfl_xor(Z, d);
  fac[q * 32 + lane] = e / Z;
  if (lane == 0) {
    gm[q] = v1;
    offs[q] = (float)i1;
    if (v1 - v2 <= TAU) {
      int pos = atomicAdd(rcount, 1);
      if (pos < 4096) rlist[pos] = q;
    }
  }
}

// ---------- candidate scan for flagged rows (decode s from P) ----------
__global__ __launch_bounds__(256) void k_cands(const int* __restrict__ rlist, const int* __restrict__ rcount,
                                               const u16* __restrict__ P, const float* __restrict__ bm1,
                                               const float* __restrict__ gm,
                                               u32* __restrict__ pairs, int* __restrict__ pcount) {
  int cnt = *rcount; if (cnt > 4096) cnt = 4096;
  for (int e = blockIdx.x; e < cnt; e += gridDim.x) {
    int q = rlist[e];
    float thr = gm[q] - 2.0f * TAU - 1e-3f;
    #pragma unroll
    for (int i = 0; i < 16; ++i) {
      int l = threadIdx.x + i * 256;
      float p = f16f(P[(size_t)q * 4096 + l]);
      float s = bm1[q * 32 + (l >> 7)] + __logf(p) * (1.0f / SCALE);
      if (s >= thr) {
        int pos = atomicAdd(pcount, 1);
        if (pos < PAIRCAP) pairs[pos] = ((u32)q << 12) | (u32)l;
      }
    }
  }
}

// ---------- GEMM2: G[q,d] = sum_l (P*fac)[q,l] * wT[d,l], split-K=4 ----------
__global__ __launch_bounds__(256, 2) void k_mfma2(
    const u16* __restrict__ P, const float* __restrict__ fac, const u16* __restrict__ Bm,
    float* __restrict__ Gpart)
{
  __shared__ u32 lds[12288];
  u16* ldsu = (u16*)lds;
  const int tid = threadIdx.x;
  const int lane = tid & 63, wid = tid >> 6;
  const int wrM = wid >> 1, wc = wid & 1;
  const int kq = lane >> 4, li = lane & 15;

  int nwg = gridDim.x * gridDim.y;       // 80
  int bid = blockIdx.y * gridDim.x + blockIdx.x;
  int cpx = nwg >> 3;
  int swz = (bid & 7) * cpx + (bid >> 3);
  int bx = swz % gridDim.x, by = swz / gridDim.x;
  const int m0 = by * 256, n0 = bx * 128;
  const int kz = blockIdx.z * 1024;

  f4v acc[8][4] = {};
  u4v av[4]; float fv[4];

#define ISSUE2(buf, k0) do {                                                             \
    _Pragma("unroll") for (int i_ = 0; i_ < 4; ++i_) {                                   \
      int s_ = tid + i_ * 256; int r_ = s_ >> 2, ks_ = s_ & 3;                           \
      int kg_ = ks_ ^ ((r_ >> 1) & 3);                                                   \
      int kk_ = (k0) + kg_ * 8;                                                          \
      av[i_] = *(const u4v*)(P + (size_t)(m0 + r_) * 4096 + kk_);                        \
      fv[i_] = fac[(m0 + r_) * 32 + (kk_ >> 7)]; }                                       \
    _Pragma("unroll") for (int i_ = 0; i_ < 2; ++i_) {                                   \
      int s_ = tid + i_ * 256; int r_ = s_ >> 2, ks_ = s_ & 3;                           \
      int kg_ = ks_ ^ ((r_ >> 1) & 3);                                                   \
      gld16(Bm + (u32)(n0 + r_) * 4096u + (u32)((k0) + kg_ * 8),                         \
            (char*)lds + (buf) * 24576 + 16384 + s_ * 16); }                             \
  } while (0)

#define WRITE2(buf) do {                                                                 \
    _Pragma("unroll") for (int i_ = 0; i_ < 4; ++i_) {                                   \
      int s_ = tid + i_ * 256;                                                           \
      union { u4v u; h8v h; } cc; cc.u = av[i_];                                         \
      _Float16 fh = (_Float16)fv[i_];                                                    \
      cc.h *= (h8v){fh, fh, fh, fh, fh, fh, fh, fh};                                     \
      *(u4v*)((char*)lds + (buf) * 24576 + s_ * 16) = cc.u; }                            \
  } while (0)

  ISSUE2(0, kz);
  WRITE2(0);
  __syncthreads();

  for (int kc = 0; kc < 32; ++kc) {
    int cur = kc & 1;
    if (kc + 1 < 32) ISSUE2(cur ^ 1, kz + (kc + 1) * 32);
    int cb = cur * 12288;
    h8v ah[8];
    #pragma unroll
    for (int mf = 0; mf < 8; ++mf) {
      int r = wrM * 128 + mf * 16 + li;
      int off = r * 32 + (kq ^ ((r >> 1) & 3)) * 8;
      ah[mf] = *(const h8v*)&ldsu[cb + off];
    }
    #pragma unroll
    for (int nf = 0; nf < 4; ++nf) {
      int r = wc * 64 + nf * 16 + li;
      int off = r * 32 + (kq ^ ((r >> 1) & 3)) * 8;
      h8v bh = *(const h8v*)&ldsu[cb + 8192 + off];
      #pragma unroll
      for (int mf = 0; mf < 8; ++mf)
        acc[mf][nf] = __builtin_amdgcn_mfma_f32_16x16x32_f16(ah[mf], bh, acc[mf][nf], 0, 0, 0);
    }
    if (kc + 1 < 32) WRITE2(cur ^ 1);
    __syncthreads();
  }

  float* Cf = Gpart + (size_t)blockIdx.z * 2359296;
  #pragma unroll
  for (int nf = 0; nf < 4; ++nf) {
    int n = n0 + wc * 64 + nf * 16 + li;
    if (n < D_) {
      #pragma unroll
      for (int mf = 0; mf < 8; ++mf) {
        int m = m0 + wrM * 128 + mf * 16 + kq * 4;
        #pragma unroll
        for (int rr = 0; rr < 4; ++rr)
          Cf[(u32)(m + rr) * (u32)D_ + n] = acc[mf][nf][rr];
      }
    }
  }
}

// ---------- f64 rescue: one wave per (q,l) pair ----------
__global__ __launch_bounds__(256) void k_rpairs(const u32* __restrict__ pairs, const int* __restrict__ pcount,
                                                const float* __restrict__ b0, const float* __restrict__ m0,
                                                const float* __restrict__ fmb, const double* __restrict__ norme,
                                                u64* __restrict__ rbest) {
  int nw = gridDim.x * 4;
  int gw = blockIdx.x * 4 + (threadIdx.x >> 6);
  int lane = threadIdx.x & 63;
  int cnt = *pcount; if (cnt > PAIRCAP) cnt = PAIRCAP;
  for (int e = gw; e < cnt; e += nw) {
    u32 pr = pairs[e];
    int q = pr >> 12, l = pr & 4095;
    int qy = q >> 6, qx = q & 63, ly = l >> 6, lx = l & 63;
    int c = lane;
    double dot = 0.0;
    #pragma unroll
    for (int t = 0; t < 9; ++t) {
      int i = t / 3, j = t - (t / 3) * 3;
      int wy = ly + i - 1, wx = lx + j - 1;
      int fy = qy + i - 1, fx = qx + j - 1;
      float wv = 0.f, fv = 0.f;
      if ((unsigned)wy < 64u && (unsigned)wx < 64u) wv = b0[(c << 12) + (wy << 6) + wx] * m0[l * 9 + t];
      if ((unsigned)fy < 64u && (unsigned)fx < 64u) fv = fmb[(c << 12) + (fy << 6) + fx];
      dot += (double)wv * (double)fv;
    }
    #pragma unroll
    for (int off = 32; off; off >>= 1) dot += __shfl_down(dot, off);
    if (lane == 0) {
      double sc = dot / norme[l];
      u64 bbits = (u64)__double_as_longlong(sc);
      if (bbits >> 63) bbits = ~bbits; else bbits |= 0x8000000000000000ull;
      u64 key = (bbits & ~0xFFFull) | (u64)(4095 - l);
      atomicMax(rbest + q, key);
    }
  }
}

// ---------- fold (1024 blocks) + rescue finalize (16 blocks) ----------
__global__ __launch_bounds__(256) void k_foldfin(const float* __restrict__ Gp, float* __restrict__ yout,
                                                 const int* __restrict__ rlist, const int* __restrict__ rcount,
                                                 const u64* __restrict__ rbest, float* __restrict__ offs) {
  if (blockIdx.x < 1024) {
    int idx = blockIdx.x * 256 + threadIdx.x;   // c*4096 + p
    int c = idx >> 12, p = idx & 4095;
    int yy = p >> 6, xx = p & 63;
    float s = 0.f;
    #pragma unroll
    for (int t = 0; t < 9; ++t) {
      int i = t / 3, j = t - (t / 3) * 3;
      int qy = yy + 1 - i, qx = xx + 1 - j;
      if ((unsigned)qy < 64u && (unsigned)qx < 64u) {
        u32 base = (u32)((qy << 6) + qx) * D_ + c * 9 + t;
        #pragma unroll
        for (int z = 0; z < 4; ++z) s += Gp[(size_t)z * 2359296 + base];
      }
    }
    yout[idx] = s;
  } else {
    int cnt = *rcount; if (cnt > 4096) cnt = 4096;
    int e = (blockIdx.x - 1024) * 256 + threadIdx.x;
    if (e < cnt) {
      int q = rlist[e];
      offs[q] = (float)(4095 - (int)(rbest[q] & 0xFFFull));
    }
  }
}

extern "C" void kernel_launch(void* const* d_in, const int* in_sizes, int n_in,
                              void* d_out, int out_size, void* d_ws, size_t ws_size,
                              hipStream_t stream) {
  const float* b_in = (const float*)d_in[0];
  const float* f_in = (const float*)d_in[1];
  const float* mask = (const float*)d_in[2];
  float* out = (float*)d_out;

  char* ws = (char*)d_ws;
  float*  mp     = (float*)(ws + 0);          // 64KB
  float*  m0buf  = (float*)(ws + 65536);      // 144KB
  float*  fm     = (float*)(ws + 212992);     // 4MB
  float*  normv  = (float*)(ws + 4407296);    // 16KB
  double* norme  = (double*)(ws + 4423680);   // 32KB
  u16*    w_h    = (u16*)(ws + 4456448);      // 4.7MB
  u16*    fp_h   = (u16*)(ws + 9175040);      // 4.7MB
  u16*    wT_h   = (u16*)(ws + 13893632);     // 5.2MB (640x4096)
  u16*    P      = (u16*)(ws + 19136512);     // 32MB fp16
  float*  bm1    = (float*)(ws + 52690944);   // 512KB
  int*    bi1    = (int*)(ws + 53215232);     // 512KB
  float*  bm2    = (float*)(ws + 53739520);   // 512KB
  float*  bsum   = (float*)(ws + 54263808);   // 512KB
  float*  fac    = (float*)(ws + 54788096);   // 512KB
  float*  gm     = (float*)(ws + 55312384);   // 16KB
  float*  Gpart  = (float*)(ws + 55328768);   // 37.7MB
  int*    rcount = (int*)(ws + 93077504);
  int*    pcount = (int*)(ws + 93077508);
  int*    rlist  = (int*)(ws + 93077760);     // 16KB
  u64*    rbest  = (u64*)(ws + 93094144);     // 32KB
  u32*    pairs  = (u32*)(ws + 93126912);     // 1MB -> ends 94175488

  k_mp<<<64, 256, 0, stream>>>(mask, mp);
  k_pre2<<<4240, 256, 0, stream>>>(f_in, mp, m0buf, fm);

  for (int b = 0; b < B_; ++b) {
    const float* bimg = b_in + (size_t)b * C_ * HW;
    const float* fmb  = fm + (size_t)b * C_ * HW;
    float* offs_b = out + (size_t)B_ * C_ * HW + (size_t)b * HW;

    k_prep<<<15376, 256, 0, stream>>>(bimg, fmb, m0buf, w_h, fp_h, wT_h,
                                      norme, normv, rcount, pcount, rbest);
    k_mfma1<<<dim3(32, 16), 256, 0, stream>>>(fp_h, w_h, normv, P, bm1, bi1, bm2, bsum);
    k_smred<<<1024, 256, 0, stream>>>(bm1, bi1, bm2, bsum, fac, gm, offs_b, rlist, rcount);
    k_mfma2<<<dim3(5, 16, 4), 256, 0, stream>>>(P, fac, wT_h, Gpart);
    k_cands<<<64, 256, 0, stream>>>(rlist, rcount, P, bm1, gm, pairs, pcount);
    k_rpairs<<<512, 256, 0, stream>>>(pairs, pcount, bimg, m0buf, fmb, norme, rbest);
    k_foldfin<<<1040, 256, 0, stream>>>(Gpart, out + (size_t)b * C_ * HW,
                                        rlist, rcount, rbest, offs_b);
  }
}

// Round 9
// 828.872 us; speedup vs baseline: 1.0818x; 1.0818x over previous
//
#include <hip/hip_runtime.h>
#include <math.h>

typedef unsigned int u32;
typedef unsigned short u16;
typedef unsigned long long u64;
typedef _Float16 h8v __attribute__((ext_vector_type(8)));
typedef float f4v __attribute__((ext_vector_type(4)));
typedef u32 u4v __attribute__((ext_vector_type(4)));

#define B_ 4
#define C_ 64
#define HW 4096
#define L_ 4096
#define D_ 576
#define MW 256
#define SCALE 10.0f
#define EPS 1e-4f
#define TAU 0.015f
#define PAIRCAP 262144

__device__ __forceinline__ u16 f16b(float x) {
  union { _Float16 h; u16 u; } c; c.h = (_Float16)x; return c.u;
}
__device__ __forceinline__ float f16f(u16 v) {
  union { u16 u; _Float16 h; } c; c.u = v; return (float)c.h;
}

__device__ __forceinline__ void gld16(const void* g, void* l) {
  __builtin_amdgcn_global_load_lds((const __attribute__((address_space(1))) void*)g,
                                   (__attribute__((address_space(3))) void*)l, 16, 0, 0);
}

// ---------- upfront kernels ----------
__global__ __launch_bounds__(256) void k_mp(const float* __restrict__ mask, float* __restrict__ mp) {
  int idx = blockIdx.x * 256 + threadIdx.x;
  int b = idx >> 12, p = idx & 4095;
  int y = p >> 6, x = p & 63;
  const float* mb = mask + (size_t)b * MW * MW;
  float s = 0.f;
  #pragma unroll
  for (int i = 0; i < 4; ++i)
    #pragma unroll
    for (int j = 0; j < 4; ++j)
      s += mb[(y * 4 + i) * MW + x * 4 + j];
  mp[idx] = s * (1.f / 16.f);
}

__global__ __launch_bounds__(256) void k_pre2(const float* __restrict__ f, const float* __restrict__ mp,
                                              float* __restrict__ m0, float* __restrict__ fm) {
  int blk = blockIdx.x;
  if (blk < 144) {
    int idx = blk * 256 + threadIdx.x;   // l*9 + t
    int l = idx / 9, t = idx - l * 9;
    int ly = l >> 6, lx = l & 63;
    int i = t / 3, j = t - i * 3;
    int yy = ly + i - 1, xx = lx + j - 1;
    float v = 0.f;
    if ((unsigned)yy < 64u && (unsigned)xx < 64u) v = mp[(yy << 6) + xx];
    m0[idx] = v;
  } else {
    int idx = (blk - 144) * 256 + threadIdx.x;
    int p = idx & 4095;
    int b = idx >> 18;
    fm[idx] = f[idx] * (1.f - mp[(b << 12) + p]);
  }
}

__device__ __forceinline__ float patch_val(const float* __restrict__ img, const float* __restrict__ m0,
                                           int l, int d) {
  int c = d / 9, t = d - c * 9;
  int ly = l >> 6, lx = l & 63;
  int i = t / 3, j = t - i * 3;
  int yy = ly + i - 1, xx = lx + j - 1;
  float v = 0.f;
  if ((unsigned)yy < 64u && (unsigned)xx < 64u) {
    v = img[(c << 12) + (yy << 6) + xx];
    if (m0) v *= m0[l * 9 + t];
  }
  return v;
}

// ---------- per-batch prep: w | norme | wT | fp | zero ----------
__global__ __launch_bounds__(256) void k_prep(const float* __restrict__ bimg, const float* __restrict__ fmb,
                                              const float* __restrict__ m0,
                                              u16* __restrict__ w_h, u16* __restrict__ fp_h,
                                              u16* __restrict__ wT_h,
                                              double* __restrict__ norme, float* __restrict__ normv,
                                              int* __restrict__ rcount, int* __restrict__ pcount,
                                              u64* __restrict__ rbest) {
  int blk = blockIdx.x;
  if (blk < 4608) {                      // w patches [l][576] fp16, paired
    int gid = blk * 256 + threadIdx.x;
    int idx = gid * 2;
    int l = idx / D_, d = idx - l * D_;
    u32 h0 = f16b(patch_val(bimg, m0, l, d));
    u32 h1 = f16b(patch_val(bimg, m0, l, d + 1));
    ((u32*)w_h)[gid] = h0 | (h1 << 16);
  } else if (blk < 5632) {               // exact f64 norm + f32 copy
    int l = (blk - 4608) * 4 + (threadIdx.x >> 6);
    int lane = threadIdx.x & 63;
    int ly = l >> 6, lx = l & 63;
    double s = 0.0;
    for (int i = lane; i < D_; i += 64) {
      int c = i / 9, t = i - c * 9;
      int ii = t / 3, jj = t - ii * 3;
      int yy = ly + ii - 1, xx = lx + jj - 1;
      if ((unsigned)yy < 64u && (unsigned)xx < 64u) {
        float wv = bimg[(c << 12) + (yy << 6) + xx] * m0[l * 9 + t];
        s += (double)wv * (double)wv;
      }
    }
    #pragma unroll
    for (int off = 32; off; off >>= 1) s += __shfl_down(s, off);
    if (lane == 0) {
      double n = sqrt(s + (double)EPS);
      norme[l] = n; normv[l] = (float)n;
    }
  } else if (blk < 10752) {              // wT [d<640][4096] fp16, paired along l
    int gid = (blk - 5632) * 256 + threadIdx.x;
    int idx = gid * 2;
    int d = idx >> 12, l = idx & 4095;
    float v0 = 0.f, v1 = 0.f;
    if (d < D_) {
      v0 = patch_val(bimg, m0, l, d);
      v1 = patch_val(bimg, m0, l + 1, d);
    }
    ((u32*)wT_h)[gid] = (u32)f16b(v0) | ((u32)f16b(v1) << 16);
  } else if (blk < 15360) {              // fp patches [q][576] fp16, paired
    int gid = (blk - 10752) * 256 + threadIdx.x;
    int idx = gid * 2;
    int l = idx / D_, d = idx - l * D_;
    u32 h0 = f16b(patch_val(fmb, nullptr, l, d));
    u32 h1 = f16b(patch_val(fmb, nullptr, l, d + 1));
    ((u32*)fp_h)[gid] = h0 | (h1 << 16);
  } else {                               // 16 blocks: zero rbest + counters
    int e = (blk - 15360) * 256 + threadIdx.x;
    rbest[e] = 0ull;
    if (e == 0) { *rcount = 0; *pcount = 0; }
  }
}

// ---------- GEMM1 + fused softmax partials (shuffle-free epilogue) ----------
// block 256(q) x 128(l), 4 waves (wave tile 128x64). A=fp [q][576], B=w [l][576].
// Emits P[q][l]=exp(10(s-v1_blk)) fp16; per-(q,j): bm1(=blk max), bi1, bsum, bflg.
#define STAGE1(buf, k0) do {                                                             \
    int bb = (buf) * 24576;                                                              \
    _Pragma("unroll") for (int i_ = 0; i_ < 4; ++i_) {                                   \
      int s_ = tid + i_ * 256; int r_ = s_ >> 2, ks_ = s_ & 3;                           \
      int kg_ = ks_ ^ ((r_ >> 1) & 3);                                                   \
      gld16(A + (u32)(m0 + r_) * 576u + (u32)((k0) + kg_ * 8),                           \
            (char*)lds + bb + s_ * 16); }                                                \
    _Pragma("unroll") for (int i_ = 0; i_ < 2; ++i_) {                                   \
      int s_ = tid + i_ * 256; int r_ = s_ >> 2, ks_ = s_ & 3;                           \
      int kg_ = ks_ ^ ((r_ >> 1) & 3);                                                   \
      gld16(Bm + (u32)(n0 + r_) * 576u + (u32)((k0) + kg_ * 8),                          \
            (char*)lds + bb + 16384 + s_ * 16); }                                        \
  } while (0)

__global__ __launch_bounds__(256, 2) void k_mfma1(
    const u16* __restrict__ A, const u16* __restrict__ Bm, const float* __restrict__ normv,
    u16* __restrict__ P, float* __restrict__ bm1, int* __restrict__ bi1,
    float* __restrict__ bsum, int* __restrict__ bflg)
{
  __shared__ u32 lds[12288];             // 48KB
  u16* ldsu = (u16*)lds;
  const int tid = threadIdx.x;
  const int lane = tid & 63, wid = tid >> 6;
  const int wrM = wid >> 1, wc = wid & 1;
  const int kq = lane >> 4, li = lane & 15;

  int nwg = gridDim.x * gridDim.y;       // 512
  int bid = blockIdx.y * gridDim.x + blockIdx.x;
  int cpx = nwg >> 3;
  int swz = (bid & 7) * cpx + (bid >> 3);
  int bx = swz % gridDim.x, by = swz / gridDim.x;
  const int m0 = by * 256, n0 = bx * 128;

  f4v acc[8][4] = {};

  STAGE1(0, 0);
  __syncthreads();

  for (int kc = 0; kc < 18; ++kc) {
    int cur = kc & 1;
    if (kc + 1 < 18) STAGE1(cur ^ 1, (kc + 1) * 32);
    int cb = cur * 12288;
    h8v ah[8];
    #pragma unroll
    for (int mf = 0; mf < 8; ++mf) {
      int r = wrM * 128 + mf * 16 + li;
      int off = r * 32 + (kq ^ ((r >> 1) & 3)) * 8;
      ah[mf] = *(const h8v*)&ldsu[cb + off];
    }
    #pragma unroll
    for (int nf = 0; nf < 4; ++nf) {
      int r = wc * 64 + nf * 16 + li;
      int off = r * 32 + (kq ^ ((r >> 1) & 3)) * 8;
      h8v bh = *(const h8v*)&ldsu[cb + 8192 + off];
      #pragma unroll
      for (int mf = 0; mf < 8; ++mf)
        acc[mf][nf] = __builtin_amdgcn_mfma_f32_16x16x32_f16(ah[mf], bh, acc[mf][nf], 0, 0, 0);
    }
    if (kc + 1 < 18) {
      asm volatile("s_waitcnt vmcnt(0)" ::: "memory");
      __builtin_amdgcn_s_barrier();
      __builtin_amdgcn_sched_barrier(0);
    }
  }
  __syncthreads();                       // loop done; reuse LDS for stats

  float* ldsf = (float*)lds;
  int*   ldsi = (int*)lds;
  // LDS map (u32 units): V1 [256][17] @0..4352, I1 @4352..8704 (dead after fold)
  //                      SUM [256][33] @0..8448 (after V1/I1 dead)
  //                      bmv @8704..8960, bidx @8960..9216, flags @9216..9472

  float invn4[4];
  #pragma unroll
  for (int nf = 0; nf < 4; ++nf) invn4[nf] = 1.0f / normv[n0 + wc * 64 + nf * 16 + li];
  #pragma unroll
  for (int mf = 0; mf < 8; ++mf)
    #pragma unroll
    for (int nf = 0; nf < 4; ++nf)
      #pragma unroll
      for (int rr = 0; rr < 4; ++rr)
        acc[mf][nf][rr] *= invn4[nf];

  // (v1,i1) per row over this block's 128 cols: two wc half-passes, row-thread fold
  float rV1 = -3.4e38f; int rI1 = 0x7fffffff;
  #pragma unroll
  for (int half = 0; half < 2; ++half) {
    if (wc == half) {
      #pragma unroll
      for (int mf = 0; mf < 8; ++mf)
        #pragma unroll
        for (int rr = 0; rr < 4; ++rr) {
          int row = wrM * 128 + mf * 16 + kq * 4 + rr;
          float tv = -3.4e38f; int ti = 0x7fffffff;
          #pragma unroll
          for (int nf = 0; nf < 4; ++nf) {
            float sv = acc[mf][nf][rr];
            int n = n0 + wc * 64 + nf * 16 + li;
            if (sv > tv || (sv == tv && n < ti)) { tv = sv; ti = n; }
          }
          ldsf[row * 17 + li] = tv;
          ldsi[4352 + row * 17 + li] = ti;
        }
    }
    __syncthreads();
    #pragma unroll
    for (int k = 0; k < 16; ++k) {
      float tv = ldsf[tid * 17 + k];
      int ti = ldsi[4352 + tid * 17 + k];
      if (tv > rV1 || (tv == rV1 && ti < rI1)) { rV1 = tv; rI1 = ti; }
    }
    __syncthreads();
  }

  // broadcast v1/i1, zero flags
  ldsf[8704 + tid] = rV1;
  ldsi[8960 + tid] = rI1;
  ldsi[9216 + tid] = 0;
  __syncthreads();

  // exp + P store + per-(row, wc*16+li) sum partial (V1/I1 regions now dead)
  #pragma unroll
  for (int mf = 0; mf < 8; ++mf)
    #pragma unroll
    for (int rr = 0; rr < 4; ++rr) {
      int row = wrM * 128 + mf * 16 + kq * 4 + rr;
      float bm = ldsf[8704 + row];
      int m = m0 + row;
      float sum4 = 0.f;
      #pragma unroll
      for (int nf = 0; nf < 4; ++nf) {
        int n = n0 + wc * 64 + nf * 16 + li;
        float p = __expf((acc[mf][nf][rr] - bm) * SCALE);
        P[(u32)m * 4096u + (u32)n] = f16b(p);
        sum4 += p;
      }
      ldsf[row * 33 + wc * 16 + li] = sum4;
    }
  __syncthreads();
  float rS = 0.f;
  #pragma unroll
  for (int k = 0; k < 32; ++k) rS += ldsf[tid * 33 + k];

  // flag: exists other element >= v1 - TAU
  #pragma unroll
  for (int mf = 0; mf < 8; ++mf)
    #pragma unroll
    for (int rr = 0; rr < 4; ++rr) {
      int row = wrM * 128 + mf * 16 + kq * 4 + rr;
      float v1 = ldsf[8704 + row];
      int i1 = ldsi[8960 + row];
      int fl = 0;
      #pragma unroll
      for (int nf = 0; nf < 4; ++nf) {
        int n = n0 + wc * 64 + nf * 16 + li;
        if (acc[mf][nf][rr] >= v1 - TAU && n != i1) fl = 1;
      }
      if (fl) atomicOr(&ldsi[9216 + row], 1);
    }
  __syncthreads();

  {
    int q = m0 + tid, j = n0 >> 7;
    bm1[q * 32 + j] = rV1;
    bi1[q * 32 + j] = rI1;
    bsum[q * 32 + j] = rS;
    bflg[q * 32 + j] = ldsi[9216 + tid];
  }
}

// ---------- softmax reduce across 32 l-blocks ----------
__global__ __launch_bounds__(256) void k_smred(const float* __restrict__ bm1, const int* __restrict__ bi1,
                                               const float* __restrict__ bsum, const int* __restrict__ bflg,
                                               float* __restrict__ fac, float* __restrict__ gm,
                                               float* __restrict__ offs,
                                               int* __restrict__ rlist, int* __restrict__ rcount) {
  int q = blockIdx.x * 4 + (threadIdx.x >> 6);
  int lane = threadIdx.x & 63;
  if (lane >= 32) return;
  float mj = bm1[q * 32 + lane];
  int   fj = bflg[q * 32 + lane];
  float v1 = mj; int i1 = bi1[q * 32 + lane];
  #pragma unroll
  for (int d = 1; d < 32; d <<= 1) {
    float ov1 = __shfl_xor(v1, d); int oi1 = __shfl_xor(i1, d);
    if (ov1 > v1 || (ov1 == v1 && oi1 < i1)) { v1 = ov1; i1 = oi1; }
  }
  // v1 = gmax, i1 = global argmax
  float e = __expf((mj - v1) * SCALE);
  float Z = bsum[q * 32 + lane] * e;
  #pragma unroll
  for (int d = 1; d < 32; d <<= 1) Z += __shfl_xor(Z, d);
  fac[q * 32 + lane] = e / Z;
  int jwin = i1 >> 7;
  int near = (lane != jwin) && (mj >= v1 - TAU);
  u64 bal = __ballot(near);
  int wflg = __shfl(fj, jwin);
  if (lane == 0) {
    gm[q] = v1;
    offs[q] = (float)i1;
    if (bal != 0ull || wflg) {
      int pos = atomicAdd(rcount, 1);
      if (pos < 4096) rlist[pos] = q;
    }
  }
}

// ---------- candidate scan for flagged rows (decode s from P) ----------
__global__ __launch_bounds__(256) void k_cands(const int* __restrict__ rlist, const int* __restrict__ rcount,
                                               const u16* __restrict__ P, const float* __restrict__ bm1,
                                               const float* __restrict__ gm,
                                               u32* __restrict__ pairs, int* __restrict__ pcount) {
  int cnt = *rcount; if (cnt > 4096) cnt = 4096;
  for (int e = blockIdx.x; e < cnt; e += gridDim.x) {
    int q = rlist[e];
    float thr = gm[q] - 2.0f * TAU - 1e-3f;
    #pragma unroll
    for (int i = 0; i < 16; ++i) {
      int l = threadIdx.x + i * 256;
      float p = f16f(P[(size_t)q * 4096 + l]);
      float s = bm1[q * 32 + (l >> 7)] + __logf(p) * (1.0f / SCALE);
      if (s >= thr) {
        int pos = atomicAdd(pcount, 1);
        if (pos < PAIRCAP) pairs[pos] = ((u32)q << 12) | (u32)l;
      }
    }
  }
}

// ---------- attn = P * fac (vectorized, 8 fp16/thread) ----------
__global__ __launch_bounds__(256) void k_attn(const u16* __restrict__ P, const float* __restrict__ fac,
                                              u16* __restrict__ attn) {
  int gid = blockIdx.x * 256 + threadIdx.x;  // 2M threads
  u4v v = ((const u4v*)P)[gid];
  int q = gid >> 9;
  int l0 = (gid & 511) * 8;
  _Float16 fh = (_Float16)fac[q * 32 + (l0 >> 7)];
  union { u4v u; h8v h; } c; c.u = v;
  c.h *= (h8v){fh, fh, fh, fh, fh, fh, fh, fh};
  ((u4v*)attn)[gid] = c.u;
}

// ---------- GEMM2: G[q,d] = attn . wT, split-K=4 (r7-proven gld16 kernel) ----------
#define STG2(buf, k0) do {                                                               \
    int bb = (buf) * 24576;                                                              \
    _Pragma("unroll") for (int i_ = 0; i_ < 4; ++i_) {                                   \
      int s_ = tid + i_ * 256; int r_ = s_ >> 2, ks_ = s_ & 3;                           \
      int kg_ = ks_ ^ ((r_ >> 1) & 3);                                                   \
      gld16(A + (u32)(m0 + r_) * 4096u + (u32)((k0) + kg_ * 8),                          \
            (char*)lds + bb + s_ * 16); }                                                \
    _Pragma("unroll") for (int i_ = 0; i_ < 2; ++i_) {                                   \
      int s_ = tid + i_ * 256; int r_ = s_ >> 2, ks_ = s_ & 3;                           \
      int kg_ = ks_ ^ ((r_ >> 1) & 3);                                                   \
      gld16(Bm + (u32)(n0 + r_) * 4096u + (u32)((k0) + kg_ * 8),                         \
            (char*)lds + bb + 16384 + s_ * 16); }                                        \
  } while (0)

__global__ __launch_bounds__(256, 2) void k_gemm2(
    const u16* __restrict__ A, const u16* __restrict__ Bm, float* __restrict__ Gpart)
{
  __shared__ u32 lds[12288];
  u16* ldsu = (u16*)lds;
  const int tid = threadIdx.x;
  const int lane = tid & 63, wid = tid >> 6;
  const int wrM = wid >> 1, wc = wid & 1;
  const int kq = lane >> 4, li = lane & 15;

  int nwg = gridDim.x * gridDim.y;       // 80
  int bid = blockIdx.y * gridDim.x + blockIdx.x;
  int cpx = nwg >> 3;
  int swz = (bid & 7) * cpx + (bid >> 3);
  int bx = swz % gridDim.x, by = swz / gridDim.x;
  const int m0 = by * 256, n0 = bx * 128;
  const int kz = blockIdx.z * 1024;

  f4v acc[8][4] = {};

  STG2(0, kz);
  __syncthreads();

  for (int kc = 0; kc < 32; ++kc) {
    int cur = kc & 1;
    if (kc + 1 < 32) STG2(cur ^ 1, kz + (kc + 1) * 32);
    int cb = cur * 12288;
    h8v ah[8];
    #pragma unroll
    for (int mf = 0; mf < 8; ++mf) {
      int r = wrM * 128 + mf * 16 + li;
      int off = r * 32 + (kq ^ ((r >> 1) & 3)) * 8;
      ah[mf] = *(const h8v*)&ldsu[cb + off];
    }
    #pragma unroll
    for (int nf = 0; nf < 4; ++nf) {
      int r = wc * 64 + nf * 16 + li;
      int off = r * 32 + (kq ^ ((r >> 1) & 3)) * 8;
      h8v bh = *(const h8v*)&ldsu[cb + 8192 + off];
      #pragma unroll
      for (int mf = 0; mf < 8; ++mf)
        acc[mf][nf] = __builtin_amdgcn_mfma_f32_16x16x32_f16(ah[mf], bh, acc[mf][nf], 0, 0, 0);
    }
    if (kc + 1 < 32) {
      asm volatile("s_waitcnt vmcnt(0)" ::: "memory");
      __builtin_amdgcn_s_barrier();
      __builtin_amdgcn_sched_barrier(0);
    }
  }

  float* Cf = Gpart + (size_t)blockIdx.z * 2359296;
  #pragma unroll
  for (int nf = 0; nf < 4; ++nf) {
    int n = n0 + wc * 64 + nf * 16 + li;
    if (n < D_) {
      #pragma unroll
      for (int mf = 0; mf < 8; ++mf) {
        int m = m0 + wrM * 128 + mf * 16 + kq * 4;
        #pragma unroll
        for (int rr = 0; rr < 4; ++rr)
          Cf[(u32)(m + rr) * (u32)D_ + n] = acc[mf][nf][rr];
      }
    }
  }
}

// ---------- f64 rescue: one wave per (q,l) pair ----------
__global__ __launch_bounds__(256) void k_rpairs(const u32* __restrict__ pairs, const int* __restrict__ pcount,
                                                const float* __restrict__ b0, const float* __restrict__ m0,
                                                const float* __restrict__ fmb, const double* __restrict__ norme,
                                                u64* __restrict__ rbest) {
  int nw = gridDim.x * 4;
  int gw = blockIdx.x * 4 + (threadIdx.x >> 6);
  int lane = threadIdx.x & 63;
  int cnt = *pcount; if (cnt > PAIRCAP) cnt = PAIRCAP;
  for (int e = gw; e < cnt; e += nw) {
    u32 pr = pairs[e];
    int q = pr >> 12, l = pr & 4095;
    int qy = q >> 6, qx = q & 63, ly = l >> 6, lx = l & 63;
    int c = lane;
    double dot = 0.0;
    #pragma unroll
    for (int t = 0; t < 9; ++t) {
      int i = t / 3, j = t - (t / 3) * 3;
      int wy = ly + i - 1, wx = lx + j - 1;
      int fy = qy + i - 1, fx = qx + j - 1;
      float wv = 0.f, fv = 0.f;
      if ((unsigned)wy < 64u && (unsigned)wx < 64u) wv = b0[(c << 12) + (wy << 6) + wx] * m0[l * 9 + t];
      if ((unsigned)fy < 64u && (unsigned)fx < 64u) fv = fmb[(c << 12) + (fy << 6) + fx];
      dot += (double)wv * (double)fv;
    }
    #pragma unroll
    for (int off = 32; off; off >>= 1) dot += __shfl_down(dot, off);
    if (lane == 0) {
      double sc = dot / norme[l];
      u64 bbits = (u64)__double_as_longlong(sc);
      if (bbits >> 63) bbits = ~bbits; else bbits |= 0x8000000000000000ull;
      u64 key = (bbits & ~0xFFFull) | (u64)(4095 - l);
      atomicMax(rbest + q, key);
    }
  }
}

// ---------- fold (1024 blocks) + rescue finalize (16 blocks) ----------
__global__ __launch_bounds__(256) void k_foldfin(const float* __restrict__ Gp, float* __restrict__ yout,
                                                 const int* __restrict__ rlist, const int* __restrict__ rcount,
                                                 const u64* __restrict__ rbest, float* __restrict__ offs) {
  if (blockIdx.x < 1024) {
    int idx = blockIdx.x * 256 + threadIdx.x;   // c*4096 + p
    int c = idx >> 12, p = idx & 4095;
    int yy = p >> 6, xx = p & 63;
    float s = 0.f;
    #pragma unroll
    for (int t = 0; t < 9; ++t) {
      int i = t / 3, j = t - (t / 3) * 3;
      int qy = yy + 1 - i, qx = xx + 1 - j;
      if ((unsigned)qy < 64u && (unsigned)qx < 64u) {
        u32 base = (u32)((qy << 6) + qx) * D_ + c * 9 + t;
        #pragma unroll
        for (int z = 0; z < 4; ++z) s += Gp[(size_t)z * 2359296 + base];
      }
    }
    yout[idx] = s;
  } else {
    int cnt = *rcount; if (cnt > 4096) cnt = 4096;
    int e = (blockIdx.x - 1024) * 256 + threadIdx.x;
    if (e < cnt) {
      int q = rlist[e];
      offs[q] = (float)(4095 - (int)(rbest[q] & 0xFFFull));
    }
  }
}

extern "C" void kernel_launch(void* const* d_in, const int* in_sizes, int n_in,
                              void* d_out, int out_size, void* d_ws, size_t ws_size,
                              hipStream_t stream) {
  const float* b_in = (const float*)d_in[0];
  const float* f_in = (const float*)d_in[1];
  const float* mask = (const float*)d_in[2];
  float* out = (float*)d_out;

  char* ws = (char*)d_ws;
  float*  mp     = (float*)(ws + 0);          // 64KB
  float*  m0buf  = (float*)(ws + 65536);      // 144KB
  float*  fm     = (float*)(ws + 212992);     // 4MB
  float*  normv  = (float*)(ws + 4407296);    // 16KB
  double* norme  = (double*)(ws + 4423680);   // 32KB
  u16*    w_h    = (u16*)(ws + 4456448);      // 4.7MB
  u16*    fp_h   = (u16*)(ws + 9175040);      // 4.7MB
  u16*    wT_h   = (u16*)(ws + 13893632);     // 5.24MB
  u16*    P      = (u16*)(ws + 19136512);     // 32MB
  u16*    attn   = (u16*)(ws + 52690944);     // 32MB
  float*  bm1    = (float*)(ws + 86245376);   // 512KB
  int*    bi1    = (int*)(ws + 86769664);     // 512KB
  float*  bsum   = (float*)(ws + 87293952);   // 512KB
  int*    bflg   = (int*)(ws + 87818240);     // 512KB
  float*  fac    = (float*)(ws + 88342528);   // 512KB
  float*  gm     = (float*)(ws + 88866816);   // 16KB
  float*  Gpart  = (float*)(ws + 88883200);   // 37.7MB
  int*    rcount = (int*)(ws + 126631936);
  int*    pcount = (int*)(ws + 126631940);
  int*    rlist  = (int*)(ws + 126632192);    // 16KB
  u64*    rbest  = (u64*)(ws + 126648576);    // 32KB
  u32*    pairs  = (u32*)(ws + 126681344);    // 1MB -> ends 127729920

  k_mp<<<64, 256, 0, stream>>>(mask, mp);
  k_pre2<<<4240, 256, 0, stream>>>(f_in, mp, m0buf, fm);

  for (int b = 0; b < B_; ++b) {
    const float* bimg = b_in + (size_t)b * C_ * HW;
    const float* fmb  = fm + (size_t)b * C_ * HW;
    float* offs_b = out + (size_t)B_ * C_ * HW + (size_t)b * HW;

    k_prep<<<15376, 256, 0, stream>>>(bimg, fmb, m0buf, w_h, fp_h, wT_h,
                                      norme, normv, rcount, pcount, rbest);
    k_mfma1<<<dim3(32, 16), 256, 0, stream>>>(fp_h, w_h, normv, P, bm1, bi1, bsum, bflg);
    k_smred<<<1024, 256, 0, stream>>>(bm1, bi1, bsum, bflg, fac, gm, offs_b, rlist, rcount);
    k_cands<<<64, 256, 0, stream>>>(rlist, rcount, P, bm1, gm, pairs, pcount);
    k_attn<<<8192, 256, 0, stream>>>(P, fac, attn);
    k_gemm2<<<dim3(5, 16, 4), 256, 0, stream>>>(attn, wT_h, Gpart);
    k_rpairs<<<512, 256, 0, stream>>>(pairs, pcount, bimg, m0buf, fmb, norme, rbest);
    k_foldfin<<<1040, 256, 0, stream>>>(Gpart, out + (size_t)b * C_ * HW,
                                        rlist, rcount, rbest, offs_b);
  }
}

// Round 10
// 683.040 us; speedup vs baseline: 1.3128x; 1.2135x over previous
//
#include <hip/hip_runtime.h>
#include <math.h>

typedef unsigned int u32;
typedef unsigned short u16;
typedef unsigned long long u64;
typedef _Float16 h8v __attribute__((ext_vector_type(8)));
typedef float f4v __attribute__((ext_vector_type(4)));
typedef u32 u4v __attribute__((ext_vector_type(4)));

#define B_ 4
#define C_ 64
#define HW 4096
#define L_ 4096
#define D_ 576
#define MW 256
#define SCALE 10.0f
#define EPS 1e-4f
#define TAU 0.015f
#define PAIRCAP 262144

__device__ __forceinline__ u16 f16b(float x) {
  union { _Float16 h; u16 u; } c; c.h = (_Float16)x; return c.u;
}
__device__ __forceinline__ float f16f(u16 v) {
  union { u16 u; _Float16 h; } c; c.u = v; return (float)c.h;
}

__device__ __forceinline__ void gld16(const void* g, void* l) {
  __builtin_amdgcn_global_load_lds((const __attribute__((address_space(1))) void*)g,
                                   (__attribute__((address_space(3))) void*)l, 16, 0, 0);
}

// ---------- upfront kernels ----------
__global__ __launch_bounds__(256) void k_mp(const float* __restrict__ mask, float* __restrict__ mp) {
  int idx = blockIdx.x * 256 + threadIdx.x;
  int b = idx >> 12, p = idx & 4095;
  int y = p >> 6, x = p & 63;
  const float* mb = mask + (size_t)b * MW * MW;
  float s = 0.f;
  #pragma unroll
  for (int i = 0; i < 4; ++i)
    #pragma unroll
    for (int j = 0; j < 4; ++j)
      s += mb[(y * 4 + i) * MW + x * 4 + j];
  mp[idx] = s * (1.f / 16.f);
}

__global__ __launch_bounds__(256) void k_pre2(const float* __restrict__ f, const float* __restrict__ mp,
                                              float* __restrict__ m0, float* __restrict__ fm) {
  int blk = blockIdx.x;
  if (blk < 144) {
    int idx = blk * 256 + threadIdx.x;   // l*9 + t
    int l = idx / 9, t = idx - l * 9;
    int ly = l >> 6, lx = l & 63;
    int i = t / 3, j = t - i * 3;
    int yy = ly + i - 1, xx = lx + j - 1;
    float v = 0.f;
    if ((unsigned)yy < 64u && (unsigned)xx < 64u) v = mp[(yy << 6) + xx];
    m0[idx] = v;
  } else {
    int idx = (blk - 144) * 256 + threadIdx.x;
    int p = idx & 4095;
    int b = idx >> 18;
    fm[idx] = f[idx] * (1.f - mp[(b << 12) + p]);
  }
}

__device__ __forceinline__ float patch_val(const float* __restrict__ img, const float* __restrict__ m0,
                                           int l, int d) {
  int c = d / 9, t = d - c * 9;
  int ly = l >> 6, lx = l & 63;
  int i = t / 3, j = t - i * 3;
  int yy = ly + i - 1, xx = lx + j - 1;
  float v = 0.f;
  if ((unsigned)yy < 64u && (unsigned)xx < 64u) {
    v = img[(c << 12) + (yy << 6) + xx];
    if (m0) v *= m0[l * 9 + t];
  }
  return v;
}

// ---------- per-batch prep: w | norme | wT | fp | zero ----------
__global__ __launch_bounds__(256) void k_prep(const float* __restrict__ bimg, const float* __restrict__ fmb,
                                              const float* __restrict__ m0,
                                              u16* __restrict__ w_h, u16* __restrict__ fp_h,
                                              u16* __restrict__ wT_h,
                                              double* __restrict__ norme, float* __restrict__ normv,
                                              int* __restrict__ rcount, int* __restrict__ pcount,
                                              u64* __restrict__ rbest) {
  int blk = blockIdx.x;
  if (blk < 4608) {                      // w patches [l][576] fp16, paired
    int gid = blk * 256 + threadIdx.x;
    int idx = gid * 2;
    int l = idx / D_, d = idx - l * D_;
    u32 h0 = f16b(patch_val(bimg, m0, l, d));
    u32 h1 = f16b(patch_val(bimg, m0, l, d + 1));
    ((u32*)w_h)[gid] = h0 | (h1 << 16);
  } else if (blk < 5632) {               // exact f64 norm + f32 copy
    int l = (blk - 4608) * 4 + (threadIdx.x >> 6);
    int lane = threadIdx.x & 63;
    int ly = l >> 6, lx = l & 63;
    double s = 0.0;
    for (int i = lane; i < D_; i += 64) {
      int c = i / 9, t = i - c * 9;
      int ii = t / 3, jj = t - ii * 3;
      int yy = ly + ii - 1, xx = lx + jj - 1;
      if ((unsigned)yy < 64u && (unsigned)xx < 64u) {
        float wv = bimg[(c << 12) + (yy << 6) + xx] * m0[l * 9 + t];
        s += (double)wv * (double)wv;
      }
    }
    #pragma unroll
    for (int off = 32; off; off >>= 1) s += __shfl_down(s, off);
    if (lane == 0) {
      double n = sqrt(s + (double)EPS);
      norme[l] = n; normv[l] = (float)n;
    }
  } else if (blk < 10752) {              // wT [d<640][4096] fp16, paired along l
    int gid = (blk - 5632) * 256 + threadIdx.x;
    int idx = gid * 2;
    int d = idx >> 12, l = idx & 4095;
    float v0 = 0.f, v1 = 0.f;
    if (d < D_) {
      v0 = patch_val(bimg, m0, l, d);
      v1 = patch_val(bimg, m0, l + 1, d);
    }
    ((u32*)wT_h)[gid] = (u32)f16b(v0) | ((u32)f16b(v1) << 16);
  } else if (blk < 15360) {              // fp patches [q][576] fp16, paired
    int gid = (blk - 10752) * 256 + threadIdx.x;
    int idx = gid * 2;
    int l = idx / D_, d = idx - l * D_;
    u32 h0 = f16b(patch_val(fmb, nullptr, l, d));
    u32 h1 = f16b(patch_val(fmb, nullptr, l, d + 1));
    ((u32*)fp_h)[gid] = h0 | (h1 << 16);
  } else {                               // 16 blocks: zero rbest + counters
    int e = (blk - 15360) * 256 + threadIdx.x;
    rbest[e] = 0ull;
    if (e == 0) { *rcount = 0; *pcount = 0; }
  }
}

// ---------- GEMM1 + fused softmax partials (lean epilogue) ----------
// block 256(q) x 128(l), 4 waves (wave tile 128x64). A=fp [q][576], B=w [l][576].
// Emits P[q][l]=exp(10(s-v1_blk)) fp16; per-(q,j): bm1(=blk max), bi1, bsum, bflg.
#define STAGE1(buf, k0) do {                                                             \
    int bb = (buf) * 24576;                                                              \
    _Pragma("unroll") for (int i_ = 0; i_ < 4; ++i_) {                                   \
      int s_ = tid + i_ * 256; int r_ = s_ >> 2, ks_ = s_ & 3;                           \
      int kg_ = ks_ ^ ((r_ >> 1) & 3);                                                   \
      gld16(A + (u32)(m0 + r_) * 576u + (u32)((k0) + kg_ * 8),                           \
            (char*)lds + bb + s_ * 16); }                                                \
    _Pragma("unroll") for (int i_ = 0; i_ < 2; ++i_) {                                   \
      int s_ = tid + i_ * 256; int r_ = s_ >> 2, ks_ = s_ & 3;                           \
      int kg_ = ks_ ^ ((r_ >> 1) & 3);                                                   \
      gld16(Bm + (u32)(n0 + r_) * 576u + (u32)((k0) + kg_ * 8),                          \
            (char*)lds + bb + 16384 + s_ * 16); }                                        \
  } while (0)

__global__ __launch_bounds__(256, 2) void k_mfma1(
    const u16* __restrict__ A, const u16* __restrict__ Bm, const float* __restrict__ normv,
    u16* __restrict__ P, float* __restrict__ bm1, int* __restrict__ bi1,
    float* __restrict__ bsum, int* __restrict__ bflg)
{
  __shared__ u32 lds[12288];             // 48KB
  u16* ldsu = (u16*)lds;
  const int tid = threadIdx.x;
  const int lane = tid & 63, wid = tid >> 6;
  const int wrM = wid >> 1, wc = wid & 1;
  const int kq = lane >> 4, li = lane & 15;

  int nwg = gridDim.x * gridDim.y;       // 512
  int bid = blockIdx.y * gridDim.x + blockIdx.x;
  int cpx = nwg >> 3;
  int swz = (bid & 7) * cpx + (bid >> 3);
  int bx = swz % gridDim.x, by = swz / gridDim.x;
  const int m0 = by * 256, n0 = bx * 128;

  f4v acc[8][4] = {};

  STAGE1(0, 0);
  __syncthreads();

  for (int kc = 0; kc < 18; ++kc) {
    int cur = kc & 1;
    if (kc + 1 < 18) STAGE1(cur ^ 1, (kc + 1) * 32);
    int cb = cur * 12288;
    h8v ah[8];
    #pragma unroll
    for (int mf = 0; mf < 8; ++mf) {
      int r = wrM * 128 + mf * 16 + li;
      int off = r * 32 + (kq ^ ((r >> 1) & 3)) * 8;
      ah[mf] = *(const h8v*)&ldsu[cb + off];
    }
    #pragma unroll
    for (int nf = 0; nf < 4; ++nf) {
      int r = wc * 64 + nf * 16 + li;
      int off = r * 32 + (kq ^ ((r >> 1) & 3)) * 8;
      h8v bh = *(const h8v*)&ldsu[cb + 8192 + off];
      #pragma unroll
      for (int mf = 0; mf < 8; ++mf)
        acc[mf][nf] = __builtin_amdgcn_mfma_f32_16x16x32_f16(ah[mf], bh, acc[mf][nf], 0, 0, 0);
    }
    if (kc + 1 < 18) {
      asm volatile("s_waitcnt vmcnt(0)" ::: "memory");
      __builtin_amdgcn_s_barrier();
      __builtin_amdgcn_sched_barrier(0);
    }
  }
  __syncthreads();                       // loop done; reuse LDS for stats

  float* ldsf = (float*)lds;
  int*   ldsi = (int*)lds;
  // u32-unit map: scratch [256][33] @0..8448 (maxes, then sums)
  //               v1 @8448..8704, i1 @8704..8960, count @8960..9216

  float invn4[4];
  #pragma unroll
  for (int nf = 0; nf < 4; ++nf) invn4[nf] = 1.0f / normv[n0 + wc * 64 + nf * 16 + li];
  #pragma unroll
  for (int mf = 0; mf < 8; ++mf)
    #pragma unroll
    for (int nf = 0; nf < 4; ++nf)
      #pragma unroll
      for (int rr = 0; rr < 4; ++rr)
        acc[mf][nf][rr] *= invn4[nf];

  // pass A: per-(row, wc*16+li) max over 4 nf cols
  #pragma unroll
  for (int mf = 0; mf < 8; ++mf)
    #pragma unroll
    for (int rr = 0; rr < 4; ++rr) {
      int row = wrM * 128 + mf * 16 + kq * 4 + rr;
      float tv = fmaxf(fmaxf(acc[mf][0][rr], acc[mf][1][rr]), fmaxf(acc[mf][2][rr], acc[mf][3][rr]));
      ldsf[row * 33 + wc * 16 + li] = tv;
    }
  __syncthreads();
  float rV1 = -3.4e38f;
  #pragma unroll
  for (int k = 0; k < 32; ++k) rV1 = fmaxf(rV1, ldsf[tid * 33 + k]);
  ldsf[8448 + tid] = rV1;
  ldsi[8704 + tid] = 0x7fffffff;
  ldsi[8960 + tid] = 0;
  __syncthreads();

  // pass C: exp + P store + sum partial + equality-argmax + near-count
  #pragma unroll
  for (int mf = 0; mf < 8; ++mf)
    #pragma unroll
    for (int rr = 0; rr < 4; ++rr) {
      int row = wrM * 128 + mf * 16 + kq * 4 + rr;
      float v1 = ldsf[8448 + row];
      int m = m0 + row;
      float sum4 = 0.f;
      int locmin = 0x7fffffff, loccnt = 0;
      #pragma unroll
      for (int nf = 0; nf < 4; ++nf) {
        float sv = acc[mf][nf][rr];
        int n = n0 + wc * 64 + nf * 16 + li;
        float p = __expf((sv - v1) * SCALE);
        P[(u32)m * 4096u + (u32)n] = f16b(p);
        sum4 += p;
        if (sv == v1 && n < locmin) locmin = n;
        if (sv >= v1 - TAU) loccnt++;
      }
      ldsf[row * 33 + wc * 16 + li] = sum4;
      if (locmin != 0x7fffffff) atomicMin(&ldsi[8704 + row], locmin);
      if (loccnt) atomicAdd(&ldsi[8960 + row], loccnt);
    }
  __syncthreads();

  {
    float rS = 0.f;
    #pragma unroll
    for (int k = 0; k < 32; ++k) rS += ldsf[tid * 33 + k];
    int q = m0 + tid, j = n0 >> 7;
    bm1[q * 32 + j] = ldsf[8448 + tid];
    bi1[q * 32 + j] = ldsi[8704 + tid];
    bsum[q * 32 + j] = rS;
    bflg[q * 32 + j] = (ldsi[8960 + tid] >= 2) ? 1 : 0;
  }
}

// ---------- softmax reduce across 32 l-blocks ----------
__global__ __launch_bounds__(256) void k_smred(const float* __restrict__ bm1, const int* __restrict__ bi1,
                                               const float* __restrict__ bsum, const int* __restrict__ bflg,
                                               float* __restrict__ fac, float* __restrict__ gm,
                                               float* __restrict__ offs,
                                               int* __restrict__ rlist, int* __restrict__ rcount) {
  int q = blockIdx.x * 4 + (threadIdx.x >> 6);
  int lane = threadIdx.x & 63;
  if (lane >= 32) return;
  float mj = bm1[q * 32 + lane];
  int   fj = bflg[q * 32 + lane];
  float v1 = mj; int i1 = bi1[q * 32 + lane];
  #pragma unroll
  for (int d = 1; d < 32; d <<= 1) {
    float ov1 = __shfl_xor(v1, d); int oi1 = __shfl_xor(i1, d);
    if (ov1 > v1 || (ov1 == v1 && oi1 < i1)) { v1 = ov1; i1 = oi1; }
  }
  // v1 = gmax, i1 = global argmax
  float e = __expf((mj - v1) * SCALE);
  float Z = bsum[q * 32 + lane] * e;
  #pragma unroll
  for (int d = 1; d < 32; d <<= 1) Z += __shfl_xor(Z, d);
  fac[q * 32 + lane] = e / Z;
  int jwin = i1 >> 7;
  int near = (lane != jwin) && (mj >= v1 - TAU);
  u64 bal = __ballot(near);
  int wflg = __shfl(fj, jwin);
  if (lane == 0) {
    gm[q] = v1;
    offs[q] = (float)i1;
    if (bal != 0ull || wflg) {
      int pos = atomicAdd(rcount, 1);
      if (pos < 4096) rlist[pos] = q;
    }
  }
}

// ---------- candidate scan: fp16 bit-compare, 1 row per block ----------
__global__ __launch_bounds__(256) void k_cands(const int* __restrict__ rlist, const int* __restrict__ rcount,
                                               const u16* __restrict__ P, const float* __restrict__ bm1,
                                               const float* __restrict__ gm,
                                               u32* __restrict__ pairs, int* __restrict__ pcount) {
  __shared__ u16 pthr[32];
  int cnt = *rcount; if (cnt > 4096) cnt = 4096;
  for (int e = blockIdx.x; e < cnt; e += gridDim.x) {
    int q = rlist[e];
    float thr = gm[q] - 2.0f * TAU - 1e-3f;
    if (threadIdx.x < 32) {
      float bmj = bm1[q * 32 + threadIdx.x];
      u16 pt;
      if (bmj < thr) pt = 0x7fff;            // block max below threshold: nothing qualifies
      else {
        u16 bits = f16b(__expf((thr - bmj) * SCALE));   // in [0.73, 1]
        pt = bits > 4 ? (u16)(bits - 4) : (u16)1;       // ULP slack
      }
      pthr[threadIdx.x] = pt;
    }
    __syncthreads();
    int l0 = threadIdx.x * 16;
    const u4v* pr = (const u4v*)(P + (size_t)q * 4096 + l0);
    u4v a = pr[0], b2 = pr[1];
    u16 pt = pthr[threadIdx.x >> 3];
    u32 wds[8] = {a[0], a[1], a[2], a[3], b2[0], b2[1], b2[2], b2[3]};
    #pragma unroll
    for (int k = 0; k < 8; ++k) {
      u16 lo = (u16)wds[k], hi = (u16)(wds[k] >> 16);
      if (lo >= pt) {
        int pos = atomicAdd(pcount, 1);
        if (pos < PAIRCAP) pairs[pos] = ((u32)q << 12) | (u32)(l0 + 2 * k);
      }
      if (hi >= pt) {
        int pos = atomicAdd(pcount, 1);
        if (pos < PAIRCAP) pairs[pos] = ((u32)q << 12) | (u32)(l0 + 2 * k + 1);
      }
    }
    __syncthreads();
  }
}

// ---------- attn = P * fac (vectorized, 8 fp16/thread) ----------
__global__ __launch_bounds__(256) void k_attn(const u16* __restrict__ P, const float* __restrict__ fac,
                                              u16* __restrict__ attn) {
  int gid = blockIdx.x * 256 + threadIdx.x;  // 2M threads
  u4v v = ((const u4v*)P)[gid];
  int q = gid >> 9;
  int l0 = (gid & 511) * 8;
  _Float16 fh = (_Float16)fac[q * 32 + (l0 >> 7)];
  union { u4v u; h8v h; } c; c.u = v;
  c.h *= (h8v){fh, fh, fh, fh, fh, fh, fh, fh};
  ((u4v*)attn)[gid] = c.u;
}

// ---------- GEMM2: G[q,d] = attn . wT, split-K=4 ----------
#define STG2(buf, k0) do {                                                               \
    int bb = (buf) * 24576;                                                              \
    _Pragma("unroll") for (int i_ = 0; i_ < 4; ++i_) {                                   \
      int s_ = tid + i_ * 256; int r_ = s_ >> 2, ks_ = s_ & 3;                           \
      int kg_ = ks_ ^ ((r_ >> 1) & 3);                                                   \
      gld16(A + (u32)(m0 + r_) * 4096u + (u32)((k0) + kg_ * 8),                          \
            (char*)lds + bb + s_ * 16); }                                                \
    _Pragma("unroll") for (int i_ = 0; i_ < 2; ++i_) {                                   \
      int s_ = tid + i_ * 256; int r_ = s_ >> 2, ks_ = s_ & 3;                           \
      int kg_ = ks_ ^ ((r_ >> 1) & 3);                                                   \
      gld16(Bm + (u32)(n0 + r_) * 4096u + (u32)((k0) + kg_ * 8),                         \
            (char*)lds + bb + 16384 + s_ * 16); }                                        \
  } while (0)

__global__ __launch_bounds__(256, 2) void k_gemm2(
    const u16* __restrict__ A, const u16* __restrict__ Bm, float* __restrict__ Gpart)
{
  __shared__ u32 lds[12288];
  u16* ldsu = (u16*)lds;
  const int tid = threadIdx.x;
  const int lane = tid & 63, wid = tid >> 6;
  const int wrM = wid >> 1, wc = wid & 1;
  const int kq = lane >> 4, li = lane & 15;

  int nwg = gridDim.x * gridDim.y;       // 80
  int bid = blockIdx.y * gridDim.x + blockIdx.x;
  int cpx = nwg >> 3;
  int swz = (bid & 7) * cpx + (bid >> 3);
  int bx = swz % gridDim.x, by = swz / gridDim.x;
  const int m0 = by * 256, n0 = bx * 128;
  const int kz = blockIdx.z * 1024;

  f4v acc[8][4] = {};

  STG2(0, kz);
  __syncthreads();

  for (int kc = 0; kc < 32; ++kc) {
    int cur = kc & 1;
    if (kc + 1 < 32) STG2(cur ^ 1, kz + (kc + 1) * 32);
    int cb = cur * 12288;
    h8v ah[8];
    #pragma unroll
    for (int mf = 0; mf < 8; ++mf) {
      int r = wrM * 128 + mf * 16 + li;
      int off = r * 32 + (kq ^ ((r >> 1) & 3)) * 8;
      ah[mf] = *(const h8v*)&ldsu[cb + off];
    }
    #pragma unroll
    for (int nf = 0; nf < 4; ++nf) {
      int r = wc * 64 + nf * 16 + li;
      int off = r * 32 + (kq ^ ((r >> 1) & 3)) * 8;
      h8v bh = *(const h8v*)&ldsu[cb + 8192 + off];
      #pragma unroll
      for (int mf = 0; mf < 8; ++mf)
        acc[mf][nf] = __builtin_amdgcn_mfma_f32_16x16x32_f16(ah[mf], bh, acc[mf][nf], 0, 0, 0);
    }
    if (kc + 1 < 32) {
      asm volatile("s_waitcnt vmcnt(0)" ::: "memory");
      __builtin_amdgcn_s_barrier();
      __builtin_amdgcn_sched_barrier(0);
    }
  }

  float* Cf = Gpart + (size_t)blockIdx.z * 2359296;
  #pragma unroll
  for (int nf = 0; nf < 4; ++nf) {
    int n = n0 + wc * 64 + nf * 16 + li;
    if (n < D_) {
      #pragma unroll
      for (int mf = 0; mf < 8; ++mf) {
        int m = m0 + wrM * 128 + mf * 16 + kq * 4;
        #pragma unroll
        for (int rr = 0; rr < 4; ++rr)
          Cf[(u32)(m + rr) * (u32)D_ + n] = acc[mf][nf][rr];
      }
    }
  }
}

// ---------- f64 rescue: one wave per (q,l) pair ----------
__global__ __launch_bounds__(256) void k_rpairs(const u32* __restrict__ pairs, const int* __restrict__ pcount,
                                                const float* __restrict__ b0, const float* __restrict__ m0,
                                                const float* __restrict__ fmb, const double* __restrict__ norme,
                                                u64* __restrict__ rbest) {
  int nw = gridDim.x * 4;
  int gw = blockIdx.x * 4 + (threadIdx.x >> 6);
  int lane = threadIdx.x & 63;
  int cnt = *pcount; if (cnt > PAIRCAP) cnt = PAIRCAP;
  for (int e = gw; e < cnt; e += nw) {
    u32 pr = pairs[e];
    int q = pr >> 12, l = pr & 4095;
    int qy = q >> 6, qx = q & 63, ly = l >> 6, lx = l & 63;
    int c = lane;
    double dot = 0.0;
    #pragma unroll
    for (int t = 0; t < 9; ++t) {
      int i = t / 3, j = t - (t / 3) * 3;
      int wy = ly + i - 1, wx = lx + j - 1;
      int fy = qy + i - 1, fx = qx + j - 1;
      float wv = 0.f, fv = 0.f;
      if ((unsigned)wy < 64u && (unsigned)wx < 64u) wv = b0[(c << 12) + (wy << 6) + wx] * m0[l * 9 + t];
      if ((unsigned)fy < 64u && (unsigned)fx < 64u) fv = fmb[(c << 12) + (fy << 6) + fx];
      dot += (double)wv * (double)fv;
    }
    #pragma unroll
    for (int off = 32; off; off >>= 1) dot += __shfl_down(dot, off);
    if (lane == 0) {
      double sc = dot / norme[l];
      u64 bbits = (u64)__double_as_longlong(sc);
      if (bbits >> 63) bbits = ~bbits; else bbits |= 0x8000000000000000ull;
      u64 key = (bbits & ~0xFFFull) | (u64)(4095 - l);
      atomicMax(rbest + q, key);
    }
  }
}

// ---------- fold (1024 blocks) + rescue finalize (16 blocks) ----------
__global__ __launch_bounds__(256) void k_foldfin(const float* __restrict__ Gp, float* __restrict__ yout,
                                                 const int* __restrict__ rlist, const int* __restrict__ rcount,
                                                 const u64* __restrict__ rbest, float* __restrict__ offs) {
  if (blockIdx.x < 1024) {
    int idx = blockIdx.x * 256 + threadIdx.x;   // c*4096 + p
    int c = idx >> 12, p = idx & 4095;
    int yy = p >> 6, xx = p & 63;
    float s = 0.f;
    #pragma unroll
    for (int t = 0; t < 9; ++t) {
      int i = t / 3, j = t - (t / 3) * 3;
      int qy = yy + 1 - i, qx = xx + 1 - j;
      if ((unsigned)qy < 64u && (unsigned)qx < 64u) {
        u32 base = (u32)((qy << 6) + qx) * D_ + c * 9 + t;
        #pragma unroll
        for (int z = 0; z < 4; ++z) s += Gp[(size_t)z * 2359296 + base];
      }
    }
    yout[idx] = s;
  } else {
    int cnt = *rcount; if (cnt > 4096) cnt = 4096;
    int e = (blockIdx.x - 1024) * 256 + threadIdx.x;
    if (e < cnt) {
      int q = rlist[e];
      offs[q] = (float)(4095 - (int)(rbest[q] & 0xFFFull));
    }
  }
}

extern "C" void kernel_launch(void* const* d_in, const int* in_sizes, int n_in,
                              void* d_out, int out_size, void* d_ws, size_t ws_size,
                              hipStream_t stream) {
  const float* b_in = (const float*)d_in[0];
  const float* f_in = (const float*)d_in[1];
  const float* mask = (const float*)d_in[2];
  float* out = (float*)d_out;

  char* ws = (char*)d_ws;
  float*  mp     = (float*)(ws + 0);          // 64KB
  float*  m0buf  = (float*)(ws + 65536);      // 144KB
  float*  fm     = (float*)(ws + 212992);     // 4MB
  float*  normv  = (float*)(ws + 4407296);    // 16KB
  double* norme  = (double*)(ws + 4423680);   // 32KB
  u16*    w_h    = (u16*)(ws + 4456448);      // 4.7MB
  u16*    fp_h   = (u16*)(ws + 9175040);      // 4.7MB
  u16*    wT_h   = (u16*)(ws + 13893632);     // 5.24MB
  u16*    P      = (u16*)(ws + 19136512);     // 32MB
  u16*    attn   = (u16*)(ws + 52690944);     // 32MB
  float*  bm1    = (float*)(ws + 86245376);   // 512KB
  int*    bi1    = (int*)(ws + 86769664);     // 512KB
  float*  bsum   = (float*)(ws + 87293952);   // 512KB
  int*    bflg   = (int*)(ws + 87818240);     // 512KB
  float*  fac    = (float*)(ws + 88342528);   // 512KB
  float*  gm     = (float*)(ws + 88866816);   // 16KB
  float*  Gpart  = (float*)(ws + 88883200);   // 37.7MB
  int*    rcount = (int*)(ws + 126631936);
  int*    pcount = (int*)(ws + 126631940);
  int*    rlist  = (int*)(ws + 126632192);    // 16KB
  u64*    rbest  = (u64*)(ws + 126648576);    // 32KB
  u32*    pairs  = (u32*)(ws + 126681344);    // 1MB -> ends 127729920

  k_mp<<<64, 256, 0, stream>>>(mask, mp);
  k_pre2<<<4240, 256, 0, stream>>>(f_in, mp, m0buf, fm);

  for (int b = 0; b < B_; ++b) {
    const float* bimg = b_in + (size_t)b * C_ * HW;
    const float* fmb  = fm + (size_t)b * C_ * HW;
    float* offs_b = out + (size_t)B_ * C_ * HW + (size_t)b * HW;

    k_prep<<<15376, 256, 0, stream>>>(bimg, fmb, m0buf, w_h, fp_h, wT_h,
                                      norme, normv, rcount, pcount, rbest);
    k_mfma1<<<dim3(32, 16), 256, 0, stream>>>(fp_h, w_h, normv, P, bm1, bi1, bsum, bflg);
    k_smred<<<1024, 256, 0, stream>>>(bm1, bi1, bsum, bflg, fac, gm, offs_b, rlist, rcount);
    k_attn<<<8192, 256, 0, stream>>>(P, fac, attn);
    k_cands<<<1024, 256, 0, stream>>>(rlist, rcount, P, bm1, gm, pairs, pcount);
    k_gemm2<<<dim3(5, 16, 4), 256, 0, stream>>>(attn, wT_h, Gpart);
    k_rpairs<<<512, 256, 0, stream>>>(pairs, pcount, bimg, m0buf, fmb, norme, rbest);
    k_foldfin<<<1040, 256, 0, stream>>>(Gpart, out + (size_t)b * C_ * HW,
                                        rlist, rcount, rbest, offs_b);
  }
}

// Round 11
// 584.153 us; speedup vs baseline: 1.5350x; 1.1693x over previous
//
#include <hip/hip_runtime.h>
#include <math.h>

typedef unsigned int u32;
typedef unsigned short u16;
typedef unsigned long long u64;
typedef _Float16 h8v __attribute__((ext_vector_type(8)));
typedef float f4v __attribute__((ext_vector_type(4)));
typedef u32 u4v __attribute__((ext_vector_type(4)));

#define B_ 4
#define C_ 64
#define HW 4096
#define L_ 4096
#define D_ 576
#define MW 256
#define SCALE 10.0f
#define EPS 1e-4f
#define TAU 0.015f
#define PAIRCAP 262144

__device__ __forceinline__ u16 f16b(float x) {
  union { _Float16 h; u16 u; } c; c.h = (_Float16)x; return c.u;
}
__device__ __forceinline__ float f16f(u16 v) {
  union { u16 u; _Float16 h; } c; c.u = v; return (float)c.h;
}

__device__ __forceinline__ void gld16(const void* g, void* l) {
  __builtin_amdgcn_global_load_lds((const __attribute__((address_space(1))) void*)g,
                                   (__attribute__((address_space(3))) void*)l, 16, 0, 0);
}

// ---------- upfront kernels ----------
__global__ __launch_bounds__(256) void k_mp(const float* __restrict__ mask, float* __restrict__ mp) {
  int idx = blockIdx.x * 256 + threadIdx.x;
  int b = idx >> 12, p = idx & 4095;
  int y = p >> 6, x = p & 63;
  const float* mb = mask + (size_t)b * MW * MW;
  float s = 0.f;
  #pragma unroll
  for (int i = 0; i < 4; ++i)
    #pragma unroll
    for (int j = 0; j < 4; ++j)
      s += mb[(y * 4 + i) * MW + x * 4 + j];
  mp[idx] = s * (1.f / 16.f);
}

__global__ __launch_bounds__(256) void k_pre2(const float* __restrict__ f, const float* __restrict__ mp,
                                              float* __restrict__ m0, float* __restrict__ fm) {
  int blk = blockIdx.x;
  if (blk < 144) {
    int idx = blk * 256 + threadIdx.x;   // l*9 + t
    int l = idx / 9, t = idx - l * 9;
    int ly = l >> 6, lx = l & 63;
    int i = t / 3, j = t - i * 3;
    int yy = ly + i - 1, xx = lx + j - 1;
    float v = 0.f;
    if ((unsigned)yy < 64u && (unsigned)xx < 64u) v = mp[(yy << 6) + xx];
    m0[idx] = v;
  } else {
    int idx = (blk - 144) * 256 + threadIdx.x;
    int p = idx & 4095;
    int b = idx >> 18;
    fm[idx] = f[idx] * (1.f - mp[(b << 12) + p]);
  }
}

__device__ __forceinline__ float patch_val(const float* __restrict__ img, const float* __restrict__ m0,
                                           int l, int d) {
  int c = d / 9, t = d - c * 9;
  int ly = l >> 6, lx = l & 63;
  int i = t / 3, j = t - i * 3;
  int yy = ly + i - 1, xx = lx + j - 1;
  float v = 0.f;
  if ((unsigned)yy < 64u && (unsigned)xx < 64u) {
    v = img[(c << 12) + (yy << 6) + xx];
    if (m0) v *= m0[l * 9 + t];
  }
  return v;
}

// ---------- per-batch prep: w | norme | wT | fp | zero ----------
__global__ __launch_bounds__(256) void k_prep(const float* __restrict__ bimg, const float* __restrict__ fmb,
                                              const float* __restrict__ m0,
                                              u16* __restrict__ w_h, u16* __restrict__ fp_h,
                                              u16* __restrict__ wT_h,
                                              double* __restrict__ norme, float* __restrict__ normv,
                                              int* __restrict__ rcount, int* __restrict__ pcount,
                                              u64* __restrict__ rbest) {
  int blk = blockIdx.x;
  if (blk < 4608) {                      // w patches [l][576] fp16, paired
    int gid = blk * 256 + threadIdx.x;
    int idx = gid * 2;
    int l = idx / D_, d = idx - l * D_;
    u32 h0 = f16b(patch_val(bimg, m0, l, d));
    u32 h1 = f16b(patch_val(bimg, m0, l, d + 1));
    ((u32*)w_h)[gid] = h0 | (h1 << 16);
  } else if (blk < 5632) {               // exact f64 norm + f32 copy
    int l = (blk - 4608) * 4 + (threadIdx.x >> 6);
    int lane = threadIdx.x & 63;
    int ly = l >> 6, lx = l & 63;
    double s = 0.0;
    for (int i = lane; i < D_; i += 64) {
      int c = i / 9, t = i - c * 9;
      int ii = t / 3, jj = t - ii * 3;
      int yy = ly + ii - 1, xx = lx + jj - 1;
      if ((unsigned)yy < 64u && (unsigned)xx < 64u) {
        float wv = bimg[(c << 12) + (yy << 6) + xx] * m0[l * 9 + t];
        s += (double)wv * (double)wv;
      }
    }
    #pragma unroll
    for (int off = 32; off; off >>= 1) s += __shfl_down(s, off);
    if (lane == 0) {
      double n = sqrt(s + (double)EPS);
      norme[l] = n; normv[l] = (float)n;
    }
  } else if (blk < 10752) {              // wT [d<640][4096] fp16, paired along l
    int gid = (blk - 5632) * 256 + threadIdx.x;
    int idx = gid * 2;
    int d = idx >> 12, l = idx & 4095;
    float v0 = 0.f, v1 = 0.f;
    if (d < D_) {
      v0 = patch_val(bimg, m0, l, d);
      v1 = patch_val(bimg, m0, l + 1, d);
    }
    ((u32*)wT_h)[gid] = (u32)f16b(v0) | ((u32)f16b(v1) << 16);
  } else if (blk < 15360) {              // fp patches [q][576] fp16, paired
    int gid = (blk - 10752) * 256 + threadIdx.x;
    int idx = gid * 2;
    int l = idx / D_, d = idx - l * D_;
    u32 h0 = f16b(patch_val(fmb, nullptr, l, d));
    u32 h1 = f16b(patch_val(fmb, nullptr, l, d + 1));
    ((u32*)fp_h)[gid] = h0 | (h1 << 16);
  } else {                               // 16 blocks: zero rbest + counters
    int e = (blk - 15360) * 256 + threadIdx.x;
    rbest[e] = 0ull;
    if (e == 0) { *rcount = 0; *pcount = 0; }
  }
}

// ---------- GEMM1 + fused softmax partials (lean epilogue) ----------
#define STAGE1(buf, k0) do {                                                             \
    int bb = (buf) * 24576;                                                              \
    _Pragma("unroll") for (int i_ = 0; i_ < 4; ++i_) {                                   \
      int s_ = tid + i_ * 256; int r_ = s_ >> 2, ks_ = s_ & 3;                           \
      int kg_ = ks_ ^ ((r_ >> 1) & 3);                                                   \
      gld16(A + (u32)(m0 + r_) * 576u + (u32)((k0) + kg_ * 8),                           \
            (char*)lds + bb + s_ * 16); }                                                \
    _Pragma("unroll") for (int i_ = 0; i_ < 2; ++i_) {                                   \
      int s_ = tid + i_ * 256; int r_ = s_ >> 2, ks_ = s_ & 3;                           \
      int kg_ = ks_ ^ ((r_ >> 1) & 3);                                                   \
      gld16(Bm + (u32)(n0 + r_) * 576u + (u32)((k0) + kg_ * 8),                          \
            (char*)lds + bb + 16384 + s_ * 16); }                                        \
  } while (0)

__global__ __launch_bounds__(256, 2) void k_mfma1(
    const u16* __restrict__ A, const u16* __restrict__ Bm, const float* __restrict__ normv,
    u16* __restrict__ P, float* __restrict__ bm1, int* __restrict__ bi1,
    float* __restrict__ bsum, int* __restrict__ bflg)
{
  __shared__ u32 lds[12288];             // 48KB
  u16* ldsu = (u16*)lds;
  const int tid = threadIdx.x;
  const int lane = tid & 63, wid = tid >> 6;
  const int wrM = wid >> 1, wc = wid & 1;
  const int kq = lane >> 4, li = lane & 15;

  int nwg = gridDim.x * gridDim.y;       // 512
  int bid = blockIdx.y * gridDim.x + blockIdx.x;
  int cpx = nwg >> 3;
  int swz = (bid & 7) * cpx + (bid >> 3);
  int bx = swz % gridDim.x, by = swz / gridDim.x;
  const int m0 = by * 256, n0 = bx * 128;

  f4v acc[8][4] = {};

  STAGE1(0, 0);
  __syncthreads();

  for (int kc = 0; kc < 18; ++kc) {
    int cur = kc & 1;
    if (kc + 1 < 18) STAGE1(cur ^ 1, (kc + 1) * 32);
    int cb = cur * 12288;
    h8v ah[8];
    #pragma unroll
    for (int mf = 0; mf < 8; ++mf) {
      int r = wrM * 128 + mf * 16 + li;
      int off = r * 32 + (kq ^ ((r >> 1) & 3)) * 8;
      ah[mf] = *(const h8v*)&ldsu[cb + off];
    }
    #pragma unroll
    for (int nf = 0; nf < 4; ++nf) {
      int r = wc * 64 + nf * 16 + li;
      int off = r * 32 + (kq ^ ((r >> 1) & 3)) * 8;
      h8v bh = *(const h8v*)&ldsu[cb + 8192 + off];
      #pragma unroll
      for (int mf = 0; mf < 8; ++mf)
        acc[mf][nf] = __builtin_amdgcn_mfma_f32_16x16x32_f16(ah[mf], bh, acc[mf][nf], 0, 0, 0);
    }
    if (kc + 1 < 18) {
      asm volatile("s_waitcnt vmcnt(0)" ::: "memory");
      __builtin_amdgcn_s_barrier();
      __builtin_amdgcn_sched_barrier(0);
    }
  }
  __syncthreads();                       // loop done; reuse LDS for stats

  float* ldsf = (float*)lds;
  int*   ldsi = (int*)lds;

  float invn4[4];
  #pragma unroll
  for (int nf = 0; nf < 4; ++nf) invn4[nf] = 1.0f / normv[n0 + wc * 64 + nf * 16 + li];
  #pragma unroll
  for (int mf = 0; mf < 8; ++mf)
    #pragma unroll
    for (int nf = 0; nf < 4; ++nf)
      #pragma unroll
      for (int rr = 0; rr < 4; ++rr)
        acc[mf][nf][rr] *= invn4[nf];

  // pass A: per-(row, wc*16+li) max over 4 nf cols
  #pragma unroll
  for (int mf = 0; mf < 8; ++mf)
    #pragma unroll
    for (int rr = 0; rr < 4; ++rr) {
      int row = wrM * 128 + mf * 16 + kq * 4 + rr;
      float tv = fmaxf(fmaxf(acc[mf][0][rr], acc[mf][1][rr]), fmaxf(acc[mf][2][rr], acc[mf][3][rr]));
      ldsf[row * 33 + wc * 16 + li] = tv;
    }
  __syncthreads();
  float rV1 = -3.4e38f;
  #pragma unroll
  for (int k = 0; k < 32; ++k) rV1 = fmaxf(rV1, ldsf[tid * 33 + k]);
  ldsf[8448 + tid] = rV1;
  ldsi[8704 + tid] = 0x7fffffff;
  ldsi[8960 + tid] = 0;
  __syncthreads();

  // pass C: exp + P store + sum partial + equality-argmax + near-count
  #pragma unroll
  for (int mf = 0; mf < 8; ++mf)
    #pragma unroll
    for (int rr = 0; rr < 4; ++rr) {
      int row = wrM * 128 + mf * 16 + kq * 4 + rr;
      float v1 = ldsf[8448 + row];
      int m = m0 + row;
      float sum4 = 0.f;
      int locmin = 0x7fffffff, loccnt = 0;
      #pragma unroll
      for (int nf = 0; nf < 4; ++nf) {
        float sv = acc[mf][nf][rr];
        int n = n0 + wc * 64 + nf * 16 + li;
        float p = __expf((sv - v1) * SCALE);
        P[(u32)m * 4096u + (u32)n] = f16b(p);
        sum4 += p;
        if (sv == v1 && n < locmin) locmin = n;
        if (sv >= v1 - TAU) loccnt++;
      }
      ldsf[row * 33 + wc * 16 + li] = sum4;
      if (locmin != 0x7fffffff) atomicMin(&ldsi[8704 + row], locmin);
      if (loccnt) atomicAdd(&ldsi[8960 + row], loccnt);
    }
  __syncthreads();

  {
    float rS = 0.f;
    #pragma unroll
    for (int k = 0; k < 32; ++k) rS += ldsf[tid * 33 + k];
    int q = m0 + tid, j = n0 >> 7;
    bm1[q * 32 + j] = ldsf[8448 + tid];
    bi1[q * 32 + j] = ldsi[8704 + tid];
    bsum[q * 32 + j] = rS;
    bflg[q * 32 + j] = (ldsi[8960 + tid] >= 2) ? 1 : 0;
  }
}

// ---------- softmax reduce across 32 l-blocks ----------
__global__ __launch_bounds__(256) void k_smred(const float* __restrict__ bm1, const int* __restrict__ bi1,
                                               const float* __restrict__ bsum, const int* __restrict__ bflg,
                                               float* __restrict__ fac, float* __restrict__ gm,
                                               float* __restrict__ offs,
                                               int* __restrict__ rlist, int* __restrict__ rcount) {
  int q = blockIdx.x * 4 + (threadIdx.x >> 6);
  int lane = threadIdx.x & 63;
  if (lane >= 32) return;
  float mj = bm1[q * 32 + lane];
  int   fj = bflg[q * 32 + lane];
  float v1 = mj; int i1 = bi1[q * 32 + lane];
  #pragma unroll
  for (int d = 1; d < 32; d <<= 1) {
    float ov1 = __shfl_xor(v1, d); int oi1 = __shfl_xor(i1, d);
    if (ov1 > v1 || (ov1 == v1 && oi1 < i1)) { v1 = ov1; i1 = oi1; }
  }
  // v1 = gmax, i1 = global argmax
  float e = __expf((mj - v1) * SCALE);
  float Z = bsum[q * 32 + lane] * e;
  #pragma unroll
  for (int d = 1; d < 32; d <<= 1) Z += __shfl_xor(Z, d);
  fac[q * 32 + lane] = e / Z;
  int jwin = i1 >> 7;
  int near = (lane != jwin) && (mj >= v1 - TAU);
  u64 bal = __ballot(near);
  int wflg = __shfl(fj, jwin);
  if (lane == 0) {
    gm[q] = v1;
    offs[q] = (float)i1;
    if (bal != 0ull || wflg) {
      int pos = atomicAdd(rcount, 1);
      if (pos < 4096) rlist[pos] = q;
    }
  }
}

// ---------- candidate scan: fp16 bit-compare, 1 row per block ----------
__global__ __launch_bounds__(256) void k_cands(const int* __restrict__ rlist, const int* __restrict__ rcount,
                                               const u16* __restrict__ P, const float* __restrict__ bm1,
                                               const float* __restrict__ gm,
                                               u32* __restrict__ pairs, int* __restrict__ pcount) {
  __shared__ u16 pthr[32];
  int cnt = *rcount; if (cnt > 4096) cnt = 4096;
  for (int e = blockIdx.x; e < cnt; e += gridDim.x) {
    int q = rlist[e];
    float thr = gm[q] - 2.0f * TAU - 1e-3f;
    if (threadIdx.x < 32) {
      float bmj = bm1[q * 32 + threadIdx.x];
      u16 pt;
      if (bmj < thr) pt = 0x7fff;            // block max below threshold: nothing qualifies
      else {
        u16 bits = f16b(__expf((thr - bmj) * SCALE));   // in [0.73, 1]
        pt = bits > 4 ? (u16)(bits - 4) : (u16)1;       // ULP slack
      }
      pthr[threadIdx.x] = pt;
    }
    __syncthreads();
    int l0 = threadIdx.x * 16;
    const u4v* pr = (const u4v*)(P + (size_t)q * 4096 + l0);
    u4v a = pr[0], b2 = pr[1];
    u16 pt = pthr[threadIdx.x >> 3];
    u32 wds[8] = {a[0], a[1], a[2], a[3], b2[0], b2[1], b2[2], b2[3]};
    #pragma unroll
    for (int k = 0; k < 8; ++k) {
      u16 lo = (u16)wds[k], hi = (u16)(wds[k] >> 16);
      if (lo >= pt) {
        int pos = atomicAdd(pcount, 1);
        if (pos < PAIRCAP) pairs[pos] = ((u32)q << 12) | (u32)(l0 + 2 * k);
      }
      if (hi >= pt) {
        int pos = atomicAdd(pcount, 1);
        if (pos < PAIRCAP) pairs[pos] = ((u32)q << 12) | (u32)(l0 + 2 * k + 1);
      }
    }
    __syncthreads();
  }
}

// ---------- attn = P * fac (vectorized, 8 fp16/thread) ----------
__global__ __launch_bounds__(256) void k_attn(const u16* __restrict__ P, const float* __restrict__ fac,
                                              u16* __restrict__ attn) {
  int gid = blockIdx.x * 256 + threadIdx.x;  // 2M threads
  u4v v = ((const u4v*)P)[gid];
  int q = gid >> 9;
  int l0 = (gid & 511) * 8;
  _Float16 fh = (_Float16)fac[q * 32 + (l0 >> 7)];
  union { u4v u; h8v h; } c; c.u = v;
  c.h *= (h8v){fh, fh, fh, fh, fh, fh, fh, fh};
  ((u4v*)attn)[gid] = c.u;
}

// ---------- GEMM2: G[z][n][q] = attn . wT (TRANSPOSED output), split-K=4 ----------
#define STG2(buf, k0) do {                                                               \
    int bb = (buf) * 24576;                                                              \
    _Pragma("unroll") for (int i_ = 0; i_ < 4; ++i_) {                                   \
      int s_ = tid + i_ * 256; int r_ = s_ >> 2, ks_ = s_ & 3;                           \
      int kg_ = ks_ ^ ((r_ >> 1) & 3);                                                   \
      gld16(A + (u32)(m0 + r_) * 4096u + (u32)((k0) + kg_ * 8),                          \
            (char*)lds + bb + s_ * 16); }                                                \
    _Pragma("unroll") for (int i_ = 0; i_ < 2; ++i_) {                                   \
      int s_ = tid + i_ * 256; int r_ = s_ >> 2, ks_ = s_ & 3;                           \
      int kg_ = ks_ ^ ((r_ >> 1) & 3);                                                   \
      gld16(Bm + (u32)(n0 + r_) * 4096u + (u32)((k0) + kg_ * 8),                         \
            (char*)lds + bb + 16384 + s_ * 16); }                                        \
  } while (0)

__global__ __launch_bounds__(256, 2) void k_gemm2(
    const u16* __restrict__ A, const u16* __restrict__ Bm, float* __restrict__ Gpart)
{
  __shared__ u32 lds[12288];
  u16* ldsu = (u16*)lds;
  const int tid = threadIdx.x;
  const int lane = tid & 63, wid = tid >> 6;
  const int wrM = wid >> 1, wc = wid & 1;
  const int kq = lane >> 4, li = lane & 15;

  int nwg = gridDim.x * gridDim.y;       // 80
  int bid = blockIdx.y * gridDim.x + blockIdx.x;
  int cpx = nwg >> 3;
  int swz = (bid & 7) * cpx + (bid >> 3);
  int bx = swz % gridDim.x, by = swz / gridDim.x;
  const int m0 = by * 256, n0 = bx * 128;
  const int kz = blockIdx.z * 1024;

  f4v acc[8][4] = {};

  STG2(0, kz);
  __syncthreads();

  for (int kc = 0; kc < 32; ++kc) {
    int cur = kc & 1;
    if (kc + 1 < 32) STG2(cur ^ 1, kz + (kc + 1) * 32);
    int cb = cur * 12288;
    h8v ah[8];
    #pragma unroll
    for (int mf = 0; mf < 8; ++mf) {
      int r = wrM * 128 + mf * 16 + li;
      int off = r * 32 + (kq ^ ((r >> 1) & 3)) * 8;
      ah[mf] = *(const h8v*)&ldsu[cb + off];
    }
    #pragma unroll
    for (int nf = 0; nf < 4; ++nf) {
      int r = wc * 64 + nf * 16 + li;
      int off = r * 32 + (kq ^ ((r >> 1) & 3)) * 8;
      h8v bh = *(const h8v*)&ldsu[cb + 8192 + off];
      #pragma unroll
      for (int mf = 0; mf < 8; ++mf)
        acc[mf][nf] = __builtin_amdgcn_mfma_f32_16x16x32_f16(ah[mf], bh, acc[mf][nf], 0, 0, 0);
    }
    if (kc + 1 < 32) {
      asm volatile("s_waitcnt vmcnt(0)" ::: "memory");
      __builtin_amdgcn_s_barrier();
      __builtin_amdgcn_sched_barrier(0);
    }
  }

  // transposed store: G[n][q], lane writes one aligned float4 (4 consecutive q)
  float* Cf = Gpart + (size_t)blockIdx.z * 2359296;
  #pragma unroll
  for (int nf = 0; nf < 4; ++nf) {
    int n = n0 + wc * 64 + nf * 16 + li;
    if (n < D_) {
      #pragma unroll
      for (int mf = 0; mf < 8; ++mf) {
        int m = m0 + wrM * 128 + mf * 16 + kq * 4;
        *(f4v*)&Cf[(u32)n * 4096u + (u32)m] = acc[mf][nf];
      }
    }
  }
}

// ---------- f64 rescue: one wave per (q,l) pair ----------
__global__ __launch_bounds__(256) void k_rpairs(const u32* __restrict__ pairs, const int* __restrict__ pcount,
                                                const float* __restrict__ b0, const float* __restrict__ m0,
                                                const float* __restrict__ fmb, const double* __restrict__ norme,
                                                u64* __restrict__ rbest) {
  int nw = gridDim.x * 4;
  int gw = blockIdx.x * 4 + (threadIdx.x >> 6);
  int lane = threadIdx.x & 63;
  int cnt = *pcount; if (cnt > PAIRCAP) cnt = PAIRCAP;
  for (int e = gw; e < cnt; e += nw) {
    u32 pr = pairs[e];
    int q = pr >> 12, l = pr & 4095;
    int qy = q >> 6, qx = q & 63, ly = l >> 6, lx = l & 63;
    int c = lane;
    double dot = 0.0;
    #pragma unroll
    for (int t = 0; t < 9; ++t) {
      int i = t / 3, j = t - (t / 3) * 3;
      int wy = ly + i - 1, wx = lx + j - 1;
      int fy = qy + i - 1, fx = qx + j - 1;
      float wv = 0.f, fv = 0.f;
      if ((unsigned)wy < 64u && (unsigned)wx < 64u) wv = b0[(c << 12) + (wy << 6) + wx] * m0[l * 9 + t];
      if ((unsigned)fy < 64u && (unsigned)fx < 64u) fv = fmb[(c << 12) + (fy << 6) + fx];
      dot += (double)wv * (double)fv;
    }
    #pragma unroll
    for (int off = 32; off; off >>= 1) dot += __shfl_down(dot, off);
    if (lane == 0) {
      double sc = dot / norme[l];
      u64 bbits = (u64)__double_as_longlong(sc);
      if (bbits >> 63) bbits = ~bbits; else bbits |= 0x8000000000000000ull;
      u64 key = (bbits & ~0xFFFull) | (u64)(4095 - l);
      atomicMax(rbest + q, key);
    }
  }
}

// ---------- fold (coalesced reads from G[z][n][q]) + rescue finalize ----------
__global__ __launch_bounds__(256) void k_foldfin(const float* __restrict__ Gp, float* __restrict__ yout,
                                                 const int* __restrict__ rlist, const int* __restrict__ rcount,
                                                 const u64* __restrict__ rbest, float* __restrict__ offs) {
  if (blockIdx.x < 1024) {
    int idx = blockIdx.x * 256 + threadIdx.x;   // c*4096 + p
    int c = idx >> 12, p = idx & 4095;
    int yy = p >> 6, xx = p & 63;
    float s = 0.f;
    #pragma unroll
    for (int t = 0; t < 9; ++t) {
      int i = t / 3, j = t - (t / 3) * 3;
      int qy = yy + 1 - i, qx = xx + 1 - j;
      if ((unsigned)qy < 64u && (unsigned)qx < 64u) {
        u32 base = (u32)(c * 9 + t) * 4096u + (u32)((qy << 6) + qx);
        #pragma unroll
        for (int z = 0; z < 4; ++z) s += Gp[(size_t)z * 2359296 + base];
      }
    }
    yout[idx] = s;
  } else {
    int cnt = *rcount; if (cnt > 4096) cnt = 4096;
    int e = (blockIdx.x - 1024) * 256 + threadIdx.x;
    if (e < cnt) {
      int q = rlist[e];
      offs[q] = (float)(4095 - (int)(rbest[q] & 0xFFFull));
    }
  }
}

extern "C" void kernel_launch(void* const* d_in, const int* in_sizes, int n_in,
                              void* d_out, int out_size, void* d_ws, size_t ws_size,
                              hipStream_t stream) {
  const float* b_in = (const float*)d_in[0];
  const float* f_in = (const float*)d_in[1];
  const float* mask = (const float*)d_in[2];
  float* out = (float*)d_out;

  char* ws = (char*)d_ws;
  float*  mp     = (float*)(ws + 0);          // 64KB
  float*  m0buf  = (float*)(ws + 65536);      // 144KB
  float*  fm     = (float*)(ws + 212992);     // 4MB
  float*  normv  = (float*)(ws + 4407296);    // 16KB
  double* norme  = (double*)(ws + 4423680);   // 32KB
  u16*    w_h    = (u16*)(ws + 4456448);      // 4.7MB
  u16*    fp_h   = (u16*)(ws + 9175040);      // 4.7MB
  u16*    wT_h   = (u16*)(ws + 13893632);     // 5.24MB
  u16*    P      = (u16*)(ws + 19136512);     // 32MB
  u16*    attn   = (u16*)(ws + 52690944);     // 32MB
  float*  bm1    = (float*)(ws + 86245376);   // 512KB
  int*    bi1    = (int*)(ws + 86769664);     // 512KB
  float*  bsum   = (float*)(ws + 87293952);   // 512KB
  int*    bflg   = (int*)(ws + 87818240);     // 512KB
  float*  fac    = (float*)(ws + 88342528);   // 512KB
  float*  gm     = (float*)(ws + 88866816);   // 16KB
  float*  Gpart  = (float*)(ws + 88883200);   // 37.7MB
  int*    rcount = (int*)(ws + 126631936);
  int*    pcount = (int*)(ws + 126631940);
  int*    rlist  = (int*)(ws + 126632192);    // 16KB
  u64*    rbest  = (u64*)(ws + 126648576);    // 32KB
  u32*    pairs  = (u32*)(ws + 126681344);    // 1MB -> ends 127729920

  k_mp<<<64, 256, 0, stream>>>(mask, mp);
  k_pre2<<<4240, 256, 0, stream>>>(f_in, mp, m0buf, fm);

  for (int b = 0; b < B_; ++b) {
    const float* bimg = b_in + (size_t)b * C_ * HW;
    const float* fmb  = fm + (size_t)b * C_ * HW;
    float* offs_b = out + (size_t)B_ * C_ * HW + (size_t)b * HW;

    k_prep<<<15376, 256, 0, stream>>>(bimg, fmb, m0buf, w_h, fp_h, wT_h,
                                      norme, normv, rcount, pcount, rbest);
    k_mfma1<<<dim3(32, 16), 256, 0, stream>>>(fp_h, w_h, normv, P, bm1, bi1, bsum, bflg);
    k_smred<<<1024, 256, 0, stream>>>(bm1, bi1, bsum, bflg, fac, gm, offs_b, rlist, rcount);
    k_attn<<<8192, 256, 0, stream>>>(P, fac, attn);
    k_cands<<<1024, 256, 0, stream>>>(rlist, rcount, P, bm1, gm, pairs, pcount);
    k_gemm2<<<dim3(5, 16, 4), 256, 0, stream>>>(attn, wT_h, Gpart);
    k_rpairs<<<512, 256, 0, stream>>>(pairs, pcount, bimg, m0buf, fmb, norme, rbest);
    k_foldfin<<<1040, 256, 0, stream>>>(Gpart, out + (size_t)b * C_ * HW,
                                        rlist, rcount, rbest, offs_b);
  }
}

// Round 12
// 583.630 us; speedup vs baseline: 1.5364x; 1.0009x over previous
//
#include <hip/hip_runtime.h>
#include <math.h>

typedef unsigned int u32;
typedef unsigned short u16;
typedef unsigned long long u64;
typedef _Float16 h8v __attribute__((ext_vector_type(8)));
typedef float f4v __attribute__((ext_vector_type(4)));
typedef u32 u4v __attribute__((ext_vector_type(4)));

#define B_ 4
#define C_ 64
#define HW 4096
#define L_ 4096
#define D_ 576
#define MW 256
#define SCALE 10.0f
#define EPS 1e-4f
#define TAU 0.015f
#define PAIRCAP 262144

__device__ __forceinline__ u16 f16b(float x) {
  union { _Float16 h; u16 u; } c; c.h = (_Float16)x; return c.u;
}
__device__ __forceinline__ float f16f(u16 v) {
  union { u16 u; _Float16 h; } c; c.u = v; return (float)c.h;
}

__device__ __forceinline__ void gld16(const void* g, void* l) {
  __builtin_amdgcn_global_load_lds((const __attribute__((address_space(1))) void*)g,
                                   (__attribute__((address_space(3))) void*)l, 16, 0, 0);
}

// ---------- upfront kernels ----------
__global__ __launch_bounds__(256) void k_mp(const float* __restrict__ mask, float* __restrict__ mp) {
  int idx = blockIdx.x * 256 + threadIdx.x;
  int b = idx >> 12, p = idx & 4095;
  int y = p >> 6, x = p & 63;
  const float* mb = mask + (size_t)b * MW * MW;
  float s = 0.f;
  #pragma unroll
  for (int i = 0; i < 4; ++i)
    #pragma unroll
    for (int j = 0; j < 4; ++j)
      s += mb[(y * 4 + i) * MW + x * 4 + j];
  mp[idx] = s * (1.f / 16.f);
}

__global__ __launch_bounds__(256) void k_pre2(const float* __restrict__ f, const float* __restrict__ mp,
                                              float* __restrict__ m0, float* __restrict__ fm) {
  int blk = blockIdx.x;
  if (blk < 144) {
    int idx = blk * 256 + threadIdx.x;   // l*9 + t
    int l = idx / 9, t = idx - l * 9;
    int ly = l >> 6, lx = l & 63;
    int i = t / 3, j = t - i * 3;
    int yy = ly + i - 1, xx = lx + j - 1;
    float v = 0.f;
    if ((unsigned)yy < 64u && (unsigned)xx < 64u) v = mp[(yy << 6) + xx];
    m0[idx] = v;
  } else {
    int idx = (blk - 144) * 256 + threadIdx.x;
    int p = idx & 4095;
    int b = idx >> 18;
    fm[idx] = f[idx] * (1.f - mp[(b << 12) + p]);
  }
}

__device__ __forceinline__ float patch_val(const float* __restrict__ img, const float* __restrict__ m0,
                                           int l, int d) {
  int c = d / 9, t = d - c * 9;
  int ly = l >> 6, lx = l & 63;
  int i = t / 3, j = t - i * 3;
  int yy = ly + i - 1, xx = lx + j - 1;
  float v = 0.f;
  if ((unsigned)yy < 64u && (unsigned)xx < 64u) {
    v = img[(c << 12) + (yy << 6) + xx];
    if (m0) v *= m0[l * 9 + t];
  }
  return v;
}

// ---------- per-batch prep: w | norme | wT | fp | zero ----------
__global__ __launch_bounds__(256) void k_prep(const float* __restrict__ bimg, const float* __restrict__ fmb,
                                              const float* __restrict__ m0,
                                              u16* __restrict__ w_h, u16* __restrict__ fp_h,
                                              u16* __restrict__ wT_h,
                                              double* __restrict__ norme, float* __restrict__ normv,
                                              int* __restrict__ rcount, int* __restrict__ pcount,
                                              u64* __restrict__ rbest) {
  int blk = blockIdx.x;
  if (blk < 4608) {                      // w patches [l][576] fp16, paired
    int gid = blk * 256 + threadIdx.x;
    int idx = gid * 2;
    int l = idx / D_, d = idx - l * D_;
    u32 h0 = f16b(patch_val(bimg, m0, l, d));
    u32 h1 = f16b(patch_val(bimg, m0, l, d + 1));
    ((u32*)w_h)[gid] = h0 | (h1 << 16);
  } else if (blk < 5632) {               // exact f64 norm + f32 copy
    int l = (blk - 4608) * 4 + (threadIdx.x >> 6);
    int lane = threadIdx.x & 63;
    int ly = l >> 6, lx = l & 63;
    double s = 0.0;
    for (int i = lane; i < D_; i += 64) {
      int c = i / 9, t = i - c * 9;
      int ii = t / 3, jj = t - ii * 3;
      int yy = ly + ii - 1, xx = lx + jj - 1;
      if ((unsigned)yy < 64u && (unsigned)xx < 64u) {
        float wv = bimg[(c << 12) + (yy << 6) + xx] * m0[l * 9 + t];
        s += (double)wv * (double)wv;
      }
    }
    #pragma unroll
    for (int off = 32; off; off >>= 1) s += __shfl_down(s, off);
    if (lane == 0) {
      double n = sqrt(s + (double)EPS);
      norme[l] = n; normv[l] = (float)n;
    }
  } else if (blk < 10752) {              // wT [d<640][4096] fp16, paired along l
    int gid = (blk - 5632) * 256 + threadIdx.x;
    int idx = gid * 2;
    int d = idx >> 12, l = idx & 4095;
    float v0 = 0.f, v1 = 0.f;
    if (d < D_) {
      v0 = patch_val(bimg, m0, l, d);
      v1 = patch_val(bimg, m0, l + 1, d);
    }
    ((u32*)wT_h)[gid] = (u32)f16b(v0) | ((u32)f16b(v1) << 16);
  } else if (blk < 15360) {              // fp patches [q][576] fp16, paired
    int gid = (blk - 10752) * 256 + threadIdx.x;
    int idx = gid * 2;
    int l = idx / D_, d = idx - l * D_;
    u32 h0 = f16b(patch_val(fmb, nullptr, l, d));
    u32 h1 = f16b(patch_val(fmb, nullptr, l, d + 1));
    ((u32*)fp_h)[gid] = h0 | (h1 << 16);
  } else {                               // 16 blocks: zero rbest + counters
    int e = (blk - 15360) * 256 + threadIdx.x;
    rbest[e] = 0ull;
    if (e == 0) { *rcount = 0; *pcount = 0; }
  }
}

// ---------- GEMM1 + fused softmax partials; 3-buffer counted-vmcnt pipeline ----------
#define STAGE1(buf, k0) do {                                                             \
    int bb = (buf) * 24576;                                                              \
    _Pragma("unroll") for (int i_ = 0; i_ < 4; ++i_) {                                   \
      int s_ = tid + i_ * 256; int r_ = s_ >> 2, ks_ = s_ & 3;                           \
      int kg_ = ks_ ^ ((r_ >> 1) & 3);                                                   \
      gld16(A + (u32)(m0 + r_) * 576u + (u32)((k0) + kg_ * 8),                           \
            (char*)lds + bb + s_ * 16); }                                                \
    _Pragma("unroll") for (int i_ = 0; i_ < 2; ++i_) {                                   \
      int s_ = tid + i_ * 256; int r_ = s_ >> 2, ks_ = s_ & 3;                           \
      int kg_ = ks_ ^ ((r_ >> 1) & 3);                                                   \
      gld16(Bm + (u32)(n0 + r_) * 576u + (u32)((k0) + kg_ * 8),                          \
            (char*)lds + bb + 16384 + s_ * 16); }                                        \
  } while (0)

__global__ __launch_bounds__(256, 2) void k_mfma1(
    const u16* __restrict__ A, const u16* __restrict__ Bm, const float* __restrict__ normv,
    u16* __restrict__ P, float* __restrict__ bm1, int* __restrict__ bi1,
    float* __restrict__ bsum, int* __restrict__ bflg)
{
  __shared__ u32 lds[18432];             // 72KB = 3 x (A 16KB + B 8KB)
  u16* ldsu = (u16*)lds;
  const int tid = threadIdx.x;
  const int lane = tid & 63, wid = tid >> 6;
  const int wrM = wid >> 1, wc = wid & 1;
  const int kq = lane >> 4, li = lane & 15;

  int nwg = gridDim.x * gridDim.y;       // 512
  int bid = blockIdx.y * gridDim.x + blockIdx.x;
  int cpx = nwg >> 3;
  int swz = (bid & 7) * cpx + (bid >> 3);
  int bx = swz % gridDim.x, by = swz / gridDim.x;
  const int m0 = by * 256, n0 = bx * 128;

  f4v acc[8][4] = {};

  STAGE1(0, 0);
  STAGE1(1, 32);

  for (int kc = 0; kc < 18; ++kc) {
    if (kc + 1 < 18) { asm volatile("s_waitcnt vmcnt(6)" ::: "memory"); }
    else             { asm volatile("s_waitcnt vmcnt(0)" ::: "memory"); }
    __builtin_amdgcn_s_barrier();
    __builtin_amdgcn_sched_barrier(0);
    if (kc + 2 < 18) STAGE1((kc + 2) % 3, (kc + 2) * 32);

    int cb = (kc % 3) * 12288;
    h8v ah[8];
    #pragma unroll
    for (int mf = 0; mf < 8; ++mf) {
      int r = wrM * 128 + mf * 16 + li;
      int off = r * 32 + (kq ^ ((r >> 1) & 3)) * 8;
      ah[mf] = *(const h8v*)&ldsu[cb + off];
    }
    #pragma unroll
    for (int nf = 0; nf < 4; ++nf) {
      int r = wc * 64 + nf * 16 + li;
      int off = r * 32 + (kq ^ ((r >> 1) & 3)) * 8;
      h8v bh = *(const h8v*)&ldsu[cb + 8192 + off];
      #pragma unroll
      for (int mf = 0; mf < 8; ++mf)
        acc[mf][nf] = __builtin_amdgcn_mfma_f32_16x16x32_f16(ah[mf], bh, acc[mf][nf], 0, 0, 0);
    }
  }
  __syncthreads();                       // loop done; reuse LDS for stats

  float* ldsf = (float*)lds;
  int*   ldsi = (int*)lds;

  float invn4[4];
  #pragma unroll
  for (int nf = 0; nf < 4; ++nf) invn4[nf] = 1.0f / normv[n0 + wc * 64 + nf * 16 + li];
  #pragma unroll
  for (int mf = 0; mf < 8; ++mf)
    #pragma unroll
    for (int nf = 0; nf < 4; ++nf)
      #pragma unroll
      for (int rr = 0; rr < 4; ++rr)
        acc[mf][nf][rr] *= invn4[nf];

  // pass A: per-(row, wc*16+li) max over 4 nf cols
  #pragma unroll
  for (int mf = 0; mf < 8; ++mf)
    #pragma unroll
    for (int rr = 0; rr < 4; ++rr) {
      int row = wrM * 128 + mf * 16 + kq * 4 + rr;
      float tv = fmaxf(fmaxf(acc[mf][0][rr], acc[mf][1][rr]), fmaxf(acc[mf][2][rr], acc[mf][3][rr]));
      ldsf[row * 33 + wc * 16 + li] = tv;
    }
  __syncthreads();
  float rV1 = -3.4e38f;
  #pragma unroll
  for (int k = 0; k < 32; ++k) rV1 = fmaxf(rV1, ldsf[tid * 33 + k]);
  ldsf[8448 + tid] = rV1;
  ldsi[8704 + tid] = 0x7fffffff;
  ldsi[8960 + tid] = 0;
  __syncthreads();

  // pass C: exp + P store + sum partial + equality-argmax + near-count
  #pragma unroll
  for (int mf = 0; mf < 8; ++mf)
    #pragma unroll
    for (int rr = 0; rr < 4; ++rr) {
      int row = wrM * 128 + mf * 16 + kq * 4 + rr;
      float v1 = ldsf[8448 + row];
      int m = m0 + row;
      float sum4 = 0.f;
      int locmin = 0x7fffffff, loccnt = 0;
      #pragma unroll
      for (int nf = 0; nf < 4; ++nf) {
        float sv = acc[mf][nf][rr];
        int n = n0 + wc * 64 + nf * 16 + li;
        float p = __expf((sv - v1) * SCALE);
        P[(u32)m * 4096u + (u32)n] = f16b(p);
        sum4 += p;
        if (sv == v1 && n < locmin) locmin = n;
        if (sv >= v1 - TAU) loccnt++;
      }
      ldsf[row * 33 + wc * 16 + li] = sum4;
      if (locmin != 0x7fffffff) atomicMin(&ldsi[8704 + row], locmin);
      if (loccnt) atomicAdd(&ldsi[8960 + row], loccnt);
    }
  __syncthreads();

  {
    float rS = 0.f;
    #pragma unroll
    for (int k = 0; k < 32; ++k) rS += ldsf[tid * 33 + k];
    int q = m0 + tid, j = n0 >> 7;
    bm1[q * 32 + j] = ldsf[8448 + tid];
    bi1[q * 32 + j] = ldsi[8704 + tid];
    bsum[q * 32 + j] = rS;
    bflg[q * 32 + j] = (ldsi[8960 + tid] >= 2) ? 1 : 0;
  }
}

// ---------- softmax reduce across 32 l-blocks ----------
__global__ __launch_bounds__(256) void k_smred(const float* __restrict__ bm1, const int* __restrict__ bi1,
                                               const float* __restrict__ bsum, const int* __restrict__ bflg,
                                               float* __restrict__ fac, float* __restrict__ gm,
                                               float* __restrict__ offs,
                                               int* __restrict__ rlist, int* __restrict__ rcount) {
  int q = blockIdx.x * 4 + (threadIdx.x >> 6);
  int lane = threadIdx.x & 63;
  if (lane >= 32) return;
  float mj = bm1[q * 32 + lane];
  int   fj = bflg[q * 32 + lane];
  float v1 = mj; int i1 = bi1[q * 32 + lane];
  #pragma unroll
  for (int d = 1; d < 32; d <<= 1) {
    float ov1 = __shfl_xor(v1, d); int oi1 = __shfl_xor(i1, d);
    if (ov1 > v1 || (ov1 == v1 && oi1 < i1)) { v1 = ov1; i1 = oi1; }
  }
  // v1 = gmax, i1 = global argmax
  float e = __expf((mj - v1) * SCALE);
  float Z = bsum[q * 32 + lane] * e;
  #pragma unroll
  for (int d = 1; d < 32; d <<= 1) Z += __shfl_xor(Z, d);
  fac[q * 32 + lane] = e / Z;
  int jwin = i1 >> 7;
  int near = (lane != jwin) && (mj >= v1 - TAU);
  u64 bal = __ballot(near);
  int wflg = __shfl(fj, jwin);
  if (lane == 0) {
    gm[q] = v1;
    offs[q] = (float)i1;
    if (bal != 0ull || wflg) {
      int pos = atomicAdd(rcount, 1);
      if (pos < 4096) rlist[pos] = q;
    }
  }
}

// ---------- candidate scan: fp16 bit-compare, 1 row per block ----------
__global__ __launch_bounds__(256) void k_cands(const int* __restrict__ rlist, const int* __restrict__ rcount,
                                               const u16* __restrict__ P, const float* __restrict__ bm1,
                                               const float* __restrict__ gm,
                                               u32* __restrict__ pairs, int* __restrict__ pcount) {
  __shared__ u16 pthr[32];
  int cnt = *rcount; if (cnt > 4096) cnt = 4096;
  for (int e = blockIdx.x; e < cnt; e += gridDim.x) {
    int q = rlist[e];
    float thr = gm[q] - 2.0f * TAU - 1e-3f;
    if (threadIdx.x < 32) {
      float bmj = bm1[q * 32 + threadIdx.x];
      u16 pt;
      if (bmj < thr) pt = 0x7fff;            // block max below threshold: nothing qualifies
      else {
        u16 bits = f16b(__expf((thr - bmj) * SCALE));   // in [0.73, 1]
        pt = bits > 4 ? (u16)(bits - 4) : (u16)1;       // ULP slack
      }
      pthr[threadIdx.x] = pt;
    }
    __syncthreads();
    int l0 = threadIdx.x * 16;
    const u4v* pr = (const u4v*)(P + (size_t)q * 4096 + l0);
    u4v a = pr[0], b2 = pr[1];
    u16 pt = pthr[threadIdx.x >> 3];
    u32 wds[8] = {a[0], a[1], a[2], a[3], b2[0], b2[1], b2[2], b2[3]};
    #pragma unroll
    for (int k = 0; k < 8; ++k) {
      u16 lo = (u16)wds[k], hi = (u16)(wds[k] >> 16);
      if (lo >= pt) {
        int pos = atomicAdd(pcount, 1);
        if (pos < PAIRCAP) pairs[pos] = ((u32)q << 12) | (u32)(l0 + 2 * k);
      }
      if (hi >= pt) {
        int pos = atomicAdd(pcount, 1);
        if (pos < PAIRCAP) pairs[pos] = ((u32)q << 12) | (u32)(l0 + 2 * k + 1);
      }
    }
    __syncthreads();
  }
}

// ---------- attn = P * fac (vectorized, 8 fp16/thread) ----------
__global__ __launch_bounds__(256) void k_attn(const u16* __restrict__ P, const float* __restrict__ fac,
                                              u16* __restrict__ attn) {
  int gid = blockIdx.x * 256 + threadIdx.x;  // 2M threads
  u4v v = ((const u4v*)P)[gid];
  int q = gid >> 9;
  int l0 = (gid & 511) * 8;
  _Float16 fh = (_Float16)fac[q * 32 + (l0 >> 7)];
  union { u4v u; h8v h; } c; c.u = v;
  c.h *= (h8v){fh, fh, fh, fh, fh, fh, fh, fh};
  ((u4v*)attn)[gid] = c.u;
}

// ---------- GEMM2: G[z][n][q] (transposed out), 3-buffer counted-vmcnt, split-K=4 ----------
#define STG2(buf, k0) do {                                                               \
    int bb = (buf) * 24576;                                                              \
    _Pragma("unroll") for (int i_ = 0; i_ < 4; ++i_) {                                   \
      int s_ = tid + i_ * 256; int r_ = s_ >> 2, ks_ = s_ & 3;                           \
      int kg_ = ks_ ^ ((r_ >> 1) & 3);                                                   \
      gld16(A + (u32)(m0 + r_) * 4096u + (u32)((k0) + kg_ * 8),                          \
            (char*)lds + bb + s_ * 16); }                                                \
    _Pragma("unroll") for (int i_ = 0; i_ < 2; ++i_) {                                   \
      int s_ = tid + i_ * 256; int r_ = s_ >> 2, ks_ = s_ & 3;                           \
      int kg_ = ks_ ^ ((r_ >> 1) & 3);                                                   \
      gld16(Bm + (u32)(n0 + r_) * 4096u + (u32)((k0) + kg_ * 8),                         \
            (char*)lds + bb + 16384 + s_ * 16); }                                        \
  } while (0)

__global__ __launch_bounds__(256, 2) void k_gemm2(
    const u16* __restrict__ A, const u16* __restrict__ Bm, float* __restrict__ Gpart)
{
  __shared__ u32 lds[18432];             // 72KB = 3 buffers
  u16* ldsu = (u16*)lds;
  const int tid = threadIdx.x;
  const int lane = tid & 63, wid = tid >> 6;
  const int wrM = wid >> 1, wc = wid & 1;
  const int kq = lane >> 4, li = lane & 15;

  int nwg = gridDim.x * gridDim.y;       // 80
  int bid = blockIdx.y * gridDim.x + blockIdx.x;
  int cpx = nwg >> 3;
  int swz = (bid & 7) * cpx + (bid >> 3);
  int bx = swz % gridDim.x, by = swz / gridDim.x;
  const int m0 = by * 256, n0 = bx * 128;
  const int kz = blockIdx.z * 1024;

  f4v acc[8][4] = {};

  STG2(0, kz);
  STG2(1, kz + 32);

  for (int kc = 0; kc < 32; ++kc) {
    if (kc + 1 < 32) { asm volatile("s_waitcnt vmcnt(6)" ::: "memory"); }
    else             { asm volatile("s_waitcnt vmcnt(0)" ::: "memory"); }
    __builtin_amdgcn_s_barrier();
    __builtin_amdgcn_sched_barrier(0);
    if (kc + 2 < 32) STG2((kc + 2) % 3, kz + (kc + 2) * 32);

    int cb = (kc % 3) * 12288;
    h8v ah[8];
    #pragma unroll
    for (int mf = 0; mf < 8; ++mf) {
      int r = wrM * 128 + mf * 16 + li;
      int off = r * 32 + (kq ^ ((r >> 1) & 3)) * 8;
      ah[mf] = *(const h8v*)&ldsu[cb + off];
    }
    #pragma unroll
    for (int nf = 0; nf < 4; ++nf) {
      int r = wc * 64 + nf * 16 + li;
      int off = r * 32 + (kq ^ ((r >> 1) & 3)) * 8;
      h8v bh = *(const h8v*)&ldsu[cb + 8192 + off];
      #pragma unroll
      for (int mf = 0; mf < 8; ++mf)
        acc[mf][nf] = __builtin_amdgcn_mfma_f32_16x16x32_f16(ah[mf], bh, acc[mf][nf], 0, 0, 0);
    }
  }

  // transposed store: G[n][q], lane writes one aligned float4 (4 consecutive q)
  float* Cf = Gpart + (size_t)blockIdx.z * 2359296;
  #pragma unroll
  for (int nf = 0; nf < 4; ++nf) {
    int n = n0 + wc * 64 + nf * 16 + li;
    if (n < D_) {
      #pragma unroll
      for (int mf = 0; mf < 8; ++mf) {
        int m = m0 + wrM * 128 + mf * 16 + kq * 4;
        *(f4v*)&Cf[(u32)n * 4096u + (u32)m] = acc[mf][nf];
      }
    }
  }
}

// ---------- f64 rescue: one wave per (q,l) pair ----------
__global__ __launch_bounds__(256) void k_rpairs(const u32* __restrict__ pairs, const int* __restrict__ pcount,
                                                const float* __restrict__ b0, const float* __restrict__ m0,
                                                const float* __restrict__ fmb, const double* __restrict__ norme,
                                                u64* __restrict__ rbest) {
  int nw = gridDim.x * 4;
  int gw = blockIdx.x * 4 + (threadIdx.x >> 6);
  int lane = threadIdx.x & 63;
  int cnt = *pcount; if (cnt > PAIRCAP) cnt = PAIRCAP;
  for (int e = gw; e < cnt; e += nw) {
    u32 pr = pairs[e];
    int q = pr >> 12, l = pr & 4095;
    int qy = q >> 6, qx = q & 63, ly = l >> 6, lx = l & 63;
    int c = lane;
    double dot = 0.0;
    #pragma unroll
    for (int t = 0; t < 9; ++t) {
      int i = t / 3, j = t - (t / 3) * 3;
      int wy = ly + i - 1, wx = lx + j - 1;
      int fy = qy + i - 1, fx = qx + j - 1;
      float wv = 0.f, fv = 0.f;
      if ((unsigned)wy < 64u && (unsigned)wx < 64u) wv = b0[(c << 12) + (wy << 6) + wx] * m0[l * 9 + t];
      if ((unsigned)fy < 64u && (unsigned)fx < 64u) fv = fmb[(c << 12) + (fy << 6) + fx];
      dot += (double)wv * (double)fv;
    }
    #pragma unroll
    for (int off = 32; off; off >>= 1) dot += __shfl_down(dot, off);
    if (lane == 0) {
      double sc = dot / norme[l];
      u64 bbits = (u64)__double_as_longlong(sc);
      if (bbits >> 63) bbits = ~bbits; else bbits |= 0x8000000000000000ull;
      u64 key = (bbits & ~0xFFFull) | (u64)(4095 - l);
      atomicMax(rbest + q, key);
    }
  }
}

// ---------- fold (coalesced reads from G[z][n][q]) + rescue finalize ----------
__global__ __launch_bounds__(256) void k_foldfin(const float* __restrict__ Gp, float* __restrict__ yout,
                                                 const int* __restrict__ rlist, const int* __restrict__ rcount,
                                                 const u64* __restrict__ rbest, float* __restrict__ offs) {
  if (blockIdx.x < 1024) {
    int idx = blockIdx.x * 256 + threadIdx.x;   // c*4096 + p
    int c = idx >> 12, p = idx & 4095;
    int yy = p >> 6, xx = p & 63;
    float s = 0.f;
    #pragma unroll
    for (int t = 0; t < 9; ++t) {
      int i = t / 3, j = t - (t / 3) * 3;
      int qy = yy + 1 - i, qx = xx + 1 - j;
      if ((unsigned)qy < 64u && (unsigned)qx < 64u) {
        u32 base = (u32)(c * 9 + t) * 4096u + (u32)((qy << 6) + qx);
        #pragma unroll
        for (int z = 0; z < 4; ++z) s += Gp[(size_t)z * 2359296 + base];
      }
    }
    yout[idx] = s;
  } else {
    int cnt = *rcount; if (cnt > 4096) cnt = 4096;
    int e = (blockIdx.x - 1024) * 256 + threadIdx.x;
    if (e < cnt) {
      int q = rlist[e];
      offs[q] = (float)(4095 - (int)(rbest[q] & 0xFFFull));
    }
  }
}

extern "C" void kernel_launch(void* const* d_in, const int* in_sizes, int n_in,
                              void* d_out, int out_size, void* d_ws, size_t ws_size,
                              hipStream_t stream) {
  const float* b_in = (const float*)d_in[0];
  const float* f_in = (const float*)d_in[1];
  const float* mask = (const float*)d_in[2];
  float* out = (float*)d_out;

  char* ws = (char*)d_ws;
  float*  mp     = (float*)(ws + 0);          // 64KB
  float*  m0buf  = (float*)(ws + 65536);      // 144KB
  float*  fm     = (float*)(ws + 212992);     // 4MB
  float*  normv  = (float*)(ws + 4407296);    // 16KB
  double* norme  = (double*)(ws + 4423680);   // 32KB
  u16*    w_h    = (u16*)(ws + 4456448);      // 4.7MB
  u16*    fp_h   = (u16*)(ws + 9175040);      // 4.7MB
  u16*    wT_h   = (u16*)(ws + 13893632);     // 5.24MB
  u16*    P      = (u16*)(ws + 19136512);     // 32MB
  u16*    attn   = (u16*)(ws + 52690944);     // 32MB
  float*  bm1    = (float*)(ws + 86245376);   // 512KB
  int*    bi1    = (int*)(ws + 86769664);     // 512KB
  float*  bsum   = (float*)(ws + 87293952);   // 512KB
  int*    bflg   = (int*)(ws + 87818240);     // 512KB
  float*  fac    = (float*)(ws + 88342528);   // 512KB
  float*  gm     = (float*)(ws + 88866816);   // 16KB
  float*  Gpart  = (float*)(ws + 88883200);   // 37.7MB
  int*    rcount = (int*)(ws + 126631936);
  int*    pcount = (int*)(ws + 126631940);
  int*    rlist  = (int*)(ws + 126632192);    // 16KB
  u64*    rbest  = (u64*)(ws + 126648576);    // 32KB
  u32*    pairs  = (u32*)(ws + 126681344);    // 1MB -> ends 127729920

  k_mp<<<64, 256, 0, stream>>>(mask, mp);
  k_pre2<<<4240, 256, 0, stream>>>(f_in, mp, m0buf, fm);

  for (int b = 0; b < B_; ++b) {
    const float* bimg = b_in + (size_t)b * C_ * HW;
    const float* fmb  = fm + (size_t)b * C_ * HW;
    float* offs_b = out + (size_t)B_ * C_ * HW + (size_t)b * HW;

    k_prep<<<15376, 256, 0, stream>>>(bimg, fmb, m0buf, w_h, fp_h, wT_h,
                                      norme, normv, rcount, pcount, rbest);
    k_mfma1<<<dim3(32, 16), 256, 0, stream>>>(fp_h, w_h, normv, P, bm1, bi1, bsum, bflg);
    k_smred<<<1024, 256, 0, stream>>>(bm1, bi1, bsum, bflg, fac, gm, offs_b, rlist, rcount);
    k_attn<<<8192, 256, 0, stream>>>(P, fac, attn);
    k_cands<<<1024, 256, 0, stream>>>(rlist, rcount, P, bm1, gm, pairs, pcount);
    k_gemm2<<<dim3(5, 16, 4), 256, 0, stream>>>(attn, wT_h, Gpart);
    k_rpairs<<<512, 256, 0, stream>>>(pairs, pcount, bimg, m0buf, fmb, norme, rbest);
    k_foldfin<<<1040, 256, 0, stream>>>(Gpart, out + (size_t)b * C_ * HW,
                                        rlist, rcount, rbest, offs_b);
  }
}